// Round 4
// baseline (680.426 us; speedup 1.0000x reference)
//
#include <hip/hip_runtime.h>
#include <hip/hip_bf16.h>

#define NSEQ 4096
#define CDIM 256
#define CQKD 32
#define LOG2E 1.4426950408889634f

typedef float v4f __attribute__((ext_vector_type(4)));
typedef short v8s __attribute__((ext_vector_type(8)));

__device__ __forceinline__ float exp2_(float x) {
#if __has_builtin(__builtin_amdgcn_exp2f)
  return __builtin_amdgcn_exp2f(x);
#else
  return exp2f(x);
#endif
}

__device__ __forceinline__ unsigned short f2bf(float x) {
  unsigned u = __builtin_bit_cast(unsigned, x);
  unsigned r = (u + 0x7FFFu + ((u >> 16) & 1u)) >> 16;
  return (unsigned short)r;
}
__device__ __forceinline__ float bf2f(unsigned short s) {
  unsigned u = ((unsigned)s) << 16;
  return __builtin_bit_cast(float, u);
}
__device__ __forceinline__ unsigned int pack_bf16(float a, float b) {
#if __has_builtin(__builtin_amdgcn_cvt_pk_bf16_f32)
  typedef __bf16 v2bf __attribute__((ext_vector_type(2)));
  v2bf r = __builtin_amdgcn_cvt_pk_bf16_f32(a, b);
  return __builtin_bit_cast(unsigned int, r);
#else
  return ((unsigned)f2bf(b) << 16) | (unsigned)f2bf(a);
#endif
}

// ---------------- weight convert (bf16; q2 pre-scaled by log2e) ----------------
__global__ __launch_bounds__(256) void convw_kernel(
    const float* __restrict__ q1w, const float* __restrict__ k1w,
    const float* __restrict__ k2w, const float* __restrict__ q2w,
    const float* __restrict__ v1w, const float* __restrict__ v2w,
    unsigned short* __restrict__ W) {
  int i = blockIdx.x * 256 + threadIdx.x;
  float v;
  if (i < 8192) v = q1w[i];
  else if (i < 16384) v = k1w[i - 8192];
  else if (i < 24576) v = k2w[i - 16384];
  else if (i < 32768) v = q2w[i - 24576] * LOG2E;
  else if (i < 98304) v = v1w[i - 32768];
  else v = v2w[i - 98304];
  W[i] = f2bf(v);
}

// ---------------- transpose+convert: [b][ch][n] fp32 -> [src][b][n][ch] bf16 ----------------
__global__ __launch_bounds__(256) void transpose_kernel(
    const float* __restrict__ x, const float* __restrict__ y,
    const float* __restrict__ z, unsigned short* __restrict__ inT) {
  __shared__ unsigned short t[64][73];
  const int src = blockIdx.z;
  const float* in = src == 0 ? x : (src == 1 ? y : z);
  const int b = blockIdx.y & 3, cht = blockIdx.y >> 2;
  const int n0 = blockIdx.x * 64, ch0 = cht * 64;
  const int tid = threadIdx.x;
  const float* ip = in + ((size_t)(b * CDIM + ch0)) * NSEQ + n0;
#pragma unroll
  for (int r = 0; r < 16; ++r) {
    int ch = r * 4 + (tid >> 6);
    int n = tid & 63;
    t[ch][n] = f2bf(ip[(size_t)ch * NSEQ + n]);
  }
  __syncthreads();
  unsigned short* op = inT + ((size_t)src * 4 + b) * NSEQ * CDIM + (size_t)n0 * CDIM + ch0;
#pragma unroll
  for (int r = 0; r < 8; ++r) {
    int n = r * 8 + (tid >> 5);
    int cp = tid & 31;
    unsigned int v = ((unsigned)t[cp * 2 + 1][n] << 16) | t[cp * 2][n];
    *(unsigned int*)(op + (size_t)n * CDIM + cp * 2) = v;
  }
}

// ---------------- MFMA projections ----------------
__global__ __launch_bounds__(256) void proj_qk_mfma(
    const unsigned short* __restrict__ inT, const unsigned short* __restrict__ Wbf,
    const float* __restrict__ q1b, const float* __restrict__ k1b,
    const float* __restrict__ k2b, unsigned short* __restrict__ Q1,
    unsigned short* __restrict__ K1, unsigned short* __restrict__ K2) {
  const int which = blockIdx.z;
  const unsigned short* Wp = Wbf + which * 8192;
  const float* bias = which == 0 ? q1b : (which == 1 ? k1b : k2b);
  unsigned short* out = which == 0 ? Q1 : (which == 1 ? K1 : K2);
  const float scale = which == 0 ? LOG2E : 1.0f;
  const int b = blockIdx.y;
  const int lane = threadIdx.x & 63, w = threadIdx.x >> 6;
  const int quad = lane >> 4, r15 = lane & 15;
  const int n0 = blockIdx.x * 64 + w * 16;
  const unsigned short* ip = inT + ((size_t)which * 4 + b) * NSEQ * CDIM;
  v4f acc[2];
  const v4f vzero = {0.f, 0.f, 0.f, 0.f};
  acc[0] = vzero; acc[1] = vzero;
#pragma unroll
  for (int cb = 0; cb < 8; ++cb) {
    v8s af = *(const v8s*)(ip + (size_t)(n0 + r15) * CDIM + cb * 32 + quad * 8);
    v8s b0 = *(const v8s*)(Wp + (0 * 16 + r15) * CDIM + cb * 32 + quad * 8);
    v8s b1 = *(const v8s*)(Wp + (1 * 16 + r15) * CDIM + cb * 32 + quad * 8);
    acc[0] = __builtin_amdgcn_mfma_f32_16x16x32_bf16(af, b0, acc[0], 0, 0, 0);
    acc[1] = __builtin_amdgcn_mfma_f32_16x16x32_bf16(af, b1, acc[1], 0, 0, 0);
  }
#pragma unroll
  for (int ot = 0; ot < 2; ++ot) {
    const float bv = bias[ot * 16 + r15];
#pragma unroll
    for (int r = 0; r < 4; ++r) {
      float v = (acc[ot][r] + bv) * scale;
      out[((size_t)b * NSEQ + n0 + quad * 4 + r) * CQKD + ot * 16 + r15] = f2bf(v);
    }
  }
}

__global__ __launch_bounds__(256) void proj_v_mfma(
    const unsigned short* __restrict__ inT, const unsigned short* __restrict__ Wbf,
    const float* __restrict__ v1b, const float* __restrict__ v2b,
    unsigned short* __restrict__ V1, unsigned short* __restrict__ V2) {
  const int which = blockIdx.z;
  const unsigned short* Wp = Wbf + 32768 + which * 65536;
  const float* bias = which == 0 ? v1b : v2b;
  const int b = blockIdx.y;
  unsigned short* out = (which == 0 ? V1 : V2) + (size_t)b * CDIM * NSEQ;
  const unsigned short* ip = inT + ((size_t)(which + 1) * 4 + b) * NSEQ * CDIM;
  const int lane = threadIdx.x & 63, w = threadIdx.x >> 6;
  const int quad = lane >> 4, r15 = lane & 15;
  const int n0 = blockIdx.x * 64 + w * 16;
  v4f acc[16];
  const v4f vzero = {0.f, 0.f, 0.f, 0.f};
#pragma unroll
  for (int ot = 0; ot < 16; ++ot) acc[ot] = vzero;
#pragma unroll
  for (int cb = 0; cb < 8; ++cb) {
    v8s af = *(const v8s*)(ip + (size_t)(n0 + r15) * CDIM + cb * 32 + quad * 8);
#pragma unroll
    for (int ot = 0; ot < 16; ++ot) {
      v8s bf = *(const v8s*)(Wp + (ot * 16 + r15) * CDIM + cb * 32 + quad * 8);
      acc[ot] = __builtin_amdgcn_mfma_f32_16x16x32_bf16(af, bf, acc[ot], 0, 0, 0);
    }
  }
#pragma unroll
  for (int ot = 0; ot < 16; ++ot) {
    const int o = ot * 16 + r15;
    const float bv = bias[o];
    uint2 pk;
    pk.x = pack_bf16(acc[ot][0] + bv, acc[ot][1] + bv);
    pk.y = pack_bf16(acc[ot][2] + bv, acc[ot][3] + bv);
    *(uint2*)(out + (size_t)o * NSEQ + n0 + quad * 4) = pk;
  }
}

// ---------------- fused double attention ----------------
// 256 threads = 4 waves: ks = w>>1 (key half, 2048 keys), ch = w&1 (channel half).
// 16 queries per block. No-max softmax: raw exp2 of (pre-log2e-scaled) scores;
// l = running per-lane sum, reduced once per layer. No rescale, no fmax chains.
__device__ __forceinline__ void attn_loop(
    const unsigned short* __restrict__ Kp, const unsigned short* __restrict__ Vp,
    unsigned short* Pl, const v8s qf, int ks, int ch, int quad, int r15,
    v4f acc[8], float& lsum) {
  const v4f vzero = {0.f, 0.f, 0.f, 0.f};
  const int key0 = ks * 2048;
  const unsigned short* vrow = Vp + (size_t)(ch * 128 + r15) * NSEQ + quad * 8;
  unsigned short* prow = Pl + r15 * 72 + quad * 4;
  const unsigned short* pread = Pl + r15 * 72 + quad * 8;
  for (int kt = 0; kt < 32; ++kt) {
    const int kb0 = key0 + kt * 64;
    v8s kf[4];
#pragma unroll
    for (int kb = 0; kb < 4; ++kb)
      kf[kb] = *(const v8s*)(Kp + (kb0 + kb * 16 + r15) * CQKD + quad * 8);
#pragma unroll
    for (int kb = 0; kb < 4; ++kb) {
      v4f st = __builtin_amdgcn_mfma_f32_16x16x32_bf16(kf[kb], qf, vzero, 0, 0, 0);
      float e0 = exp2_(st[0]), e1 = exp2_(st[1]), e2 = exp2_(st[2]), e3 = exp2_(st[3]);
      lsum += (e0 + e1) + (e2 + e3);
      uint2 pk;
      pk.x = pack_bf16(e0, e1);
      pk.y = pack_bf16(e2, e3);
      *(uint2*)(prow + kb * 16) = pk;
    }
    v8s pf0 = *(const v8s*)(pread);
    v8s pf1 = *(const v8s*)(pread + 32);
#pragma unroll
    for (int t = 0; t < 8; ++t) {
      v8s vf0 = *(const v8s*)(vrow + (size_t)(t * 16) * NSEQ + kb0);
      v8s vf1 = *(const v8s*)(vrow + (size_t)(t * 16) * NSEQ + kb0 + 32);
      acc[t] = __builtin_amdgcn_mfma_f32_16x16x32_bf16(vf0, pf0, acc[t], 0, 0, 0);
      acc[t] = __builtin_amdgcn_mfma_f32_16x16x32_bf16(vf1, pf1, acc[t], 0, 0, 0);
    }
  }
}

// merge ks partials: after this, ks==0 waves hold full O; lf = full denominator
__device__ __forceinline__ void merge2(
    v4f acc[8], float lsum, float* mergeO, float (*lbuf)[16],
    int ks, int ch, int quad, int r15, float& lf) {
  lsum += __shfl_xor(lsum, 16);
  lsum += __shfl_xor(lsum, 32);
  if (ch == 0 && quad == 0) lbuf[ks][r15] = lsum;
  __syncthreads();  // also ensures all P reads done before mergeO overwrites P area
  lf = lbuf[0][r15] + lbuf[1][r15];
  if (ks == 1) {
    float* mo = mergeO + ch * (128 * 17);
#pragma unroll
    for (int t = 0; t < 8; ++t)
#pragma unroll
      for (int r = 0; r < 4; ++r)
        mo[(t * 16 + quad * 4 + r) * 17 + r15] = acc[t][r];
  }
  __syncthreads();
  if (ks == 0) {
    const float* mo = mergeO + ch * (128 * 17);
#pragma unroll
    for (int t = 0; t < 8; ++t)
#pragma unroll
      for (int r = 0; r < 4; ++r)
        acc[t][r] += mo[(t * 16 + quad * 4 + r) * 17 + r15];
  }
}

__global__ __launch_bounds__(256, 4) void fused_attn_kernel(
    const unsigned short* __restrict__ Q1g, const unsigned short* __restrict__ K1g,
    const unsigned short* __restrict__ V1g, const unsigned short* __restrict__ K2g,
    const unsigned short* __restrict__ V2g, const unsigned short* __restrict__ W2g,
    const float* __restrict__ x, const float* __restrict__ q2b,
    const float* __restrict__ g1p, const float* __restrict__ g2p,
    float* __restrict__ outp) {
  __shared__ __align__(16) char uarea[17408];   // P (4x2304=9216B) / mergeO (17408B), phase-disjoint
  __shared__ __align__(16) unsigned short out1T[16 * 260];  // out1 tile [q][c], stride 260
  __shared__ __align__(16) unsigned short q2s[16 * 32];     // q2 tile [q][o]
  __shared__ float lbuf[2][16];

  const int tid = threadIdx.x;
  const int lane = tid & 63;
  const int w = tid >> 6;     // 0..3
  const int ks = w >> 1;      // key half
  const int ch = w & 1;       // channel half
  const int quad = lane >> 4;
  const int r15 = lane & 15;
  const int b = blockIdx.x & 3;
  const int n0 = (blockIdx.x >> 2) * 16;

  unsigned short* Pl = (unsigned short*)uarea + w * (16 * 72);
  float* mergeO = (float*)uarea;

  const float g1 = g1p[0];
  const float g2 = g2p[0];

  const unsigned short* Qp  = Q1g + (size_t)b * NSEQ * CQKD;
  const unsigned short* K1p = K1g + (size_t)b * NSEQ * CQKD;
  const unsigned short* K2p = K2g + (size_t)b * NSEQ * CQKD;
  const unsigned short* V1p = V1g + (size_t)b * CDIM * NSEQ;
  const unsigned short* V2p = V2g + (size_t)b * CDIM * NSEQ;

  v8s qf = *(const v8s*)(Qp + (n0 + r15) * CQKD + quad * 8);

  v4f acc[8];
  const v4f vzero = {0.f, 0.f, 0.f, 0.f};
#pragma unroll
  for (int t = 0; t < 8; ++t) acc[t] = vzero;
  float lsum = 0.f, lf;

  // ---- layer 1 ----
  attn_loop(K1p, V1p, Pl, qf, ks, ch, quad, r15, acc, lsum);
  merge2(acc, lsum, mergeO, lbuf, ks, ch, quad, r15, lf);
  if (ks == 0) {
    const float rinv = 1.0f / lf;
#pragma unroll
    for (int t = 0; t < 8; ++t) {
      const int c = ch * 128 + t * 16 + quad * 4;
      float o0 = g1 * (acc[t][0] * rinv) + x[((size_t)b * CDIM + c + 0) * NSEQ + n0 + r15];
      float o1 = g1 * (acc[t][1] * rinv) + x[((size_t)b * CDIM + c + 1) * NSEQ + n0 + r15];
      float o2 = g1 * (acc[t][2] * rinv) + x[((size_t)b * CDIM + c + 2) * NSEQ + n0 + r15];
      float o3 = g1 * (acc[t][3] * rinv) + x[((size_t)b * CDIM + c + 3) * NSEQ + n0 + r15];
      uint2 pk;
      pk.x = pack_bf16(o0, o1);
      pk.y = pack_bf16(o2, o3);
      *(uint2*)(out1T + r15 * 260 + c) = pk;
    }
  }
  __syncthreads();

  // ---- q2 projection (MFMA): q2[o][q] = W2[o][:] . out1[q][:], W2 pre-scaled ----
  if (w < 2) {
    v4f qacc = vzero;
#pragma unroll
    for (int cb = 0; cb < 8; ++cb) {
      v8s af = *(const v8s*)(W2g + (w * 16 + r15) * CDIM + cb * 32 + quad * 8);
      v8s bf = *(const v8s*)(out1T + r15 * 260 + cb * 32 + quad * 8);
      qacc = __builtin_amdgcn_mfma_f32_16x16x32_bf16(af, bf, qacc, 0, 0, 0);
    }
    // D: col=q=r15, row=o = w*16 + quad*4 + r
    const int o0 = w * 16 + quad * 4;
    float b0 = q2b[o0 + 0] * LOG2E, b1 = q2b[o0 + 1] * LOG2E;
    float b2 = q2b[o0 + 2] * LOG2E, b3 = q2b[o0 + 3] * LOG2E;
    uint2 pk;
    pk.x = pack_bf16(qacc[0] + b0, qacc[1] + b1);
    pk.y = pack_bf16(qacc[2] + b2, qacc[3] + b3);
    *(uint2*)(q2s + r15 * 32 + o0) = pk;
  }
  __syncthreads();

  // ---- layer 2 ----
  qf = *(const v8s*)(q2s + r15 * 32 + quad * 8);
#pragma unroll
  for (int t = 0; t < 8; ++t) acc[t] = vzero;
  lsum = 0.f;
  attn_loop(K2p, V2p, Pl, qf, ks, ch, quad, r15, acc, lsum);
  merge2(acc, lsum, mergeO, lbuf, ks, ch, quad, r15, lf);
  if (ks == 0) {
    const float rinv = 1.0f / lf;
#pragma unroll
    for (int t = 0; t < 8; ++t) {
      const int c = ch * 128 + t * 16 + quad * 4;
#pragma unroll
      for (int r = 0; r < 4; ++r) {
        float res = bf2f(out1T[r15 * 260 + c + r]);
        outp[((size_t)b * CDIM + c + r) * NSEQ + n0 + r15] = g2 * (acc[t][r] * rinv) + res;
      }
    }
  }
}

extern "C" void kernel_launch(void* const* d_in, const int* in_sizes, int n_in,
                              void* d_out, int out_size, void* d_ws, size_t ws_size,
                              hipStream_t stream) {
  const float* x   = (const float*)d_in[0];
  const float* y   = (const float*)d_in[1];
  const float* z   = (const float*)d_in[2];
  const float* q1w = (const float*)d_in[3];
  const float* q1b = (const float*)d_in[4];
  const float* k1w = (const float*)d_in[5];
  const float* k1b = (const float*)d_in[6];
  const float* v1w = (const float*)d_in[7];
  const float* v1b = (const float*)d_in[8];
  const float* g1  = (const float*)d_in[9];
  const float* q2w = (const float*)d_in[10];
  const float* q2b = (const float*)d_in[11];
  const float* k2w = (const float*)d_in[12];
  const float* k2b = (const float*)d_in[13];
  const float* v2w = (const float*)d_in[14];
  const float* v2b = (const float*)d_in[15];
  const float* g2  = (const float*)d_in[16];
  char* ws = (char*)d_ws;
  unsigned short* inT = (unsigned short*)(ws);                    // 25,165,824 B
  unsigned short* Wbf = (unsigned short*)(ws + 25165824);         // 327,680 B
  unsigned short* Q1  = (unsigned short*)(ws + 25493504);
  unsigned short* K1  = (unsigned short*)(ws + 26542080);
  unsigned short* K2  = (unsigned short*)(ws + 27590656);
  unsigned short* V1  = (unsigned short*)(ws + 28639232);
  unsigned short* V2  = (unsigned short*)(ws + 37027840);
  float* outp = (float*)d_out;

  convw_kernel<<<dim3(640), 256, 0, stream>>>(q1w, k1w, k2w, q2w, v1w, v2w, Wbf);
  transpose_kernel<<<dim3(64, 16, 3), 256, 0, stream>>>(x, y, z, inT);
  proj_qk_mfma<<<dim3(64, 4, 3), 256, 0, stream>>>(inT, Wbf, q1b, k1b, k2b, Q1, K1, K2);
  proj_v_mfma<<<dim3(64, 4, 2), 256, 0, stream>>>(inT, Wbf, v1b, v2b, V1, V2);
  fused_attn_kernel<<<dim3(1024), 256, 0, stream>>>(Q1, K1, V1, K2, V2, Wbf + 24576, x,
                                                    q2b, g1, g2, outp);
}

// Round 5
// 436.503 us; speedup vs baseline: 1.5588x; 1.5588x over previous
//
#include <hip/hip_runtime.h>
#include <hip/hip_bf16.h>

#define NSEQ 4096
#define CDIM 256
#define CQKD 32
#define LOG2E 1.4426950408889634f

typedef float v4f __attribute__((ext_vector_type(4)));
typedef float v16f __attribute__((ext_vector_type(16)));
typedef short v8s __attribute__((ext_vector_type(8)));

__device__ __forceinline__ float exp2_(float x) { return exp2f(x); }

__device__ __forceinline__ unsigned short f2bf(float x) {
  unsigned u = __builtin_bit_cast(unsigned, x);
  unsigned r = (u + 0x7FFFu + ((u >> 16) & 1u)) >> 16;
  return (unsigned short)r;
}
__device__ __forceinline__ float bf2f(unsigned short s) {
  unsigned u = ((unsigned)s) << 16;
  return __builtin_bit_cast(float, u);
}
__device__ __forceinline__ unsigned int pack_bf16(float a, float b) {
#if __has_builtin(__builtin_amdgcn_cvt_pk_bf16_f32)
  typedef __bf16 v2bf __attribute__((ext_vector_type(2)));
  v2bf r = __builtin_amdgcn_cvt_pk_bf16_f32(a, b);
  return __builtin_bit_cast(unsigned int, r);
#else
  return ((unsigned)f2bf(b) << 16) | (unsigned)f2bf(a);
#endif
}

// ---------------- weight convert (bf16; q2 pre-scaled by log2e) ----------------
__global__ __launch_bounds__(256) void convw_kernel(
    const float* __restrict__ q1w, const float* __restrict__ k1w,
    const float* __restrict__ k2w, const float* __restrict__ q2w,
    const float* __restrict__ v1w, const float* __restrict__ v2w,
    unsigned short* __restrict__ W) {
  int i = blockIdx.x * 256 + threadIdx.x;
  float v;
  if (i < 8192) v = q1w[i];
  else if (i < 16384) v = k1w[i - 8192];
  else if (i < 24576) v = k2w[i - 16384];
  else if (i < 32768) v = q2w[i - 24576] * LOG2E;
  else if (i < 98304) v = v1w[i - 32768];
  else v = v2w[i - 98304];
  W[i] = f2bf(v);
}

// ---------------- transpose+convert: [b][ch][n] fp32 -> [src][b][n][ch] bf16 ----------------
__global__ __launch_bounds__(256) void transpose_kernel(
    const float* __restrict__ x, const float* __restrict__ y,
    const float* __restrict__ z, unsigned short* __restrict__ inT) {
  __shared__ unsigned short t[64][73];
  const int src = blockIdx.z;
  const float* in = src == 0 ? x : (src == 1 ? y : z);
  const int b = blockIdx.y & 3, cht = blockIdx.y >> 2;
  const int n0 = blockIdx.x * 64, ch0 = cht * 64;
  const int tid = threadIdx.x;
  const float* ip = in + ((size_t)(b * CDIM + ch0)) * NSEQ + n0;
#pragma unroll
  for (int r = 0; r < 16; ++r) {
    int ch = r * 4 + (tid >> 6);
    int n = tid & 63;
    t[ch][n] = f2bf(ip[(size_t)ch * NSEQ + n]);
  }
  __syncthreads();
  unsigned short* op = inT + ((size_t)src * 4 + b) * NSEQ * CDIM + (size_t)n0 * CDIM + ch0;
#pragma unroll
  for (int r = 0; r < 8; ++r) {
    int n = r * 8 + (tid >> 5);
    int cp = tid & 31;
    unsigned int v = ((unsigned)t[cp * 2 + 1][n] << 16) | t[cp * 2][n];
    *(unsigned int*)(op + (size_t)n * CDIM + cp * 2) = v;
  }
}

// ---------------- MFMA projections ----------------
__global__ __launch_bounds__(256) void proj_qk_mfma(
    const unsigned short* __restrict__ inT, const unsigned short* __restrict__ Wbf,
    const float* __restrict__ q1b, const float* __restrict__ k1b,
    const float* __restrict__ k2b, unsigned short* __restrict__ Q1,
    unsigned short* __restrict__ K1, unsigned short* __restrict__ K2) {
  const int which = blockIdx.z;
  const unsigned short* Wp = Wbf + which * 8192;
  const float* bias = which == 0 ? q1b : (which == 1 ? k1b : k2b);
  unsigned short* out = which == 0 ? Q1 : (which == 1 ? K1 : K2);
  const float scale = which == 0 ? LOG2E : 1.0f;
  const int b = blockIdx.y;
  const int lane = threadIdx.x & 63, w = threadIdx.x >> 6;
  const int quad = lane >> 4, r15 = lane & 15;
  const int n0 = blockIdx.x * 64 + w * 16;
  const unsigned short* ip = inT + ((size_t)which * 4 + b) * NSEQ * CDIM;
  v4f acc[2];
  const v4f vzero = {0.f, 0.f, 0.f, 0.f};
  acc[0] = vzero; acc[1] = vzero;
#pragma unroll
  for (int cb = 0; cb < 8; ++cb) {
    v8s af = *(const v8s*)(ip + (size_t)(n0 + r15) * CDIM + cb * 32 + quad * 8);
    v8s b0 = *(const v8s*)(Wp + (0 * 16 + r15) * CDIM + cb * 32 + quad * 8);
    v8s b1 = *(const v8s*)(Wp + (1 * 16 + r15) * CDIM + cb * 32 + quad * 8);
    acc[0] = __builtin_amdgcn_mfma_f32_16x16x32_bf16(af, b0, acc[0], 0, 0, 0);
    acc[1] = __builtin_amdgcn_mfma_f32_16x16x32_bf16(af, b1, acc[1], 0, 0, 0);
  }
#pragma unroll
  for (int ot = 0; ot < 2; ++ot) {
    const float bv = bias[ot * 16 + r15];
#pragma unroll
    for (int r = 0; r < 4; ++r) {
      float v = (acc[ot][r] + bv) * scale;
      out[((size_t)b * NSEQ + n0 + quad * 4 + r) * CQKD + ot * 16 + r15] = f2bf(v);
    }
  }
}

__global__ __launch_bounds__(256, 2) void proj_v_mfma(
    const unsigned short* __restrict__ inT, const unsigned short* __restrict__ Wbf,
    const float* __restrict__ v1b, const float* __restrict__ v2b,
    unsigned short* __restrict__ V1, unsigned short* __restrict__ V2) {
  const int which = blockIdx.z;
  const unsigned short* Wp = Wbf + 32768 + which * 65536;
  const float* bias = which == 0 ? v1b : v2b;
  const int b = blockIdx.y;
  unsigned short* out = (which == 0 ? V1 : V2) + (size_t)b * CDIM * NSEQ;
  const unsigned short* ip = inT + ((size_t)(which + 1) * 4 + b) * NSEQ * CDIM;
  const int lane = threadIdx.x & 63, w = threadIdx.x >> 6;
  const int quad = lane >> 4, r15 = lane & 15;
  const int n0 = blockIdx.x * 64 + w * 16;
  v4f acc[16];
  const v4f vzero = {0.f, 0.f, 0.f, 0.f};
#pragma unroll
  for (int ot = 0; ot < 16; ++ot) acc[ot] = vzero;
#pragma unroll
  for (int cb = 0; cb < 8; ++cb) {
    v8s af = *(const v8s*)(ip + (size_t)(n0 + r15) * CDIM + cb * 32 + quad * 8);
#pragma unroll
    for (int ot = 0; ot < 16; ++ot) {
      v8s bf = *(const v8s*)(Wp + (ot * 16 + r15) * CDIM + cb * 32 + quad * 8);
      acc[ot] = __builtin_amdgcn_mfma_f32_16x16x32_bf16(af, bf, acc[ot], 0, 0, 0);
    }
  }
#pragma unroll
  for (int ot = 0; ot < 16; ++ot) {
    const int o = ot * 16 + r15;
    const float bv = bias[o];
    uint2 pk;
    pk.x = pack_bf16(acc[ot][0] + bv, acc[ot][1] + bv);
    pk.y = pack_bf16(acc[ot][2] + bv, acc[ot][3] + bv);
    *(uint2*)(out + (size_t)o * NSEQ + n0 + quad * 4) = pk;
  }
}

// ---------------- fused double attention ----------------
// 256 threads = 4 waves: ks = w>>1 (key half, 2048 keys), chh = w&1 (channel half).
// 32 queries/block. V fragments (16) issued at tile top -> in flight across the
// S/exp2/LDS phase; K double-buffered. PV uses 32x32x16 MFMA (O = 128ch x 32q/wave).
__device__ __forceinline__ void attn_loop(
    const unsigned short* __restrict__ Kp, const unsigned short* __restrict__ Vp,
    unsigned short* Pl, const v8s qf0, const v8s qf1, int ks, int chh, int lane,
    v16f acc[4], float lsum[2]) {
  const v4f vzero4 = {0.f, 0.f, 0.f, 0.f};
  const int quad = (lane >> 4) & 3, r15 = lane & 15;
  const int l31 = lane & 31, lh = lane >> 5;
  const int key0 = ks * 2048;
  const unsigned short* vbase = Vp + (size_t)(chh * 128 + l31) * NSEQ + lh * 8;
  unsigned short* pw = Pl + r15 * 72 + quad * 4;
  const unsigned short* pr = Pl + l31 * 72 + lh * 8;
  v8s kf[4], kn[4];
#pragma unroll
  for (int kb = 0; kb < 4; ++kb)
    kf[kb] = *(const v8s*)(Kp + (size_t)(key0 + kb * 16 + r15) * CQKD + quad * 8);
  for (int kt = 0; kt < 32; ++kt) {
    const int kb0 = key0 + kt * 64;
    // V fragments for this tile: issue all 16 now, consumed at PV below
    v8s vf[16];
#pragma unroll
    for (int t = 0; t < 4; ++t)
#pragma unroll
      for (int s = 0; s < 4; ++s)
        vf[t * 4 + s] = *(const v8s*)(vbase + (size_t)t * 32 * NSEQ + kb0 + s * 16);
    // prefetch next K tile
    const int ktn = (kt + 1) & 31;
#pragma unroll
    for (int kb = 0; kb < 4; ++kb)
      kn[kb] = *(const v8s*)(Kp + (size_t)(key0 + ktn * 64 + kb * 16 + r15) * CQKD + quad * 8);
    // S^T = K.Q^T, exp2, pack to P[q][key]
#pragma unroll
    for (int qt = 0; qt < 2; ++qt) {
      const v8s qf = qt ? qf1 : qf0;
#pragma unroll
      for (int kb = 0; kb < 4; ++kb) {
        v4f st = __builtin_amdgcn_mfma_f32_16x16x32_bf16(kf[kb], qf, vzero4, 0, 0, 0);
        float e0 = exp2_(st[0]), e1 = exp2_(st[1]), e2 = exp2_(st[2]), e3 = exp2_(st[3]);
        lsum[qt] += (e0 + e1) + (e2 + e3);
        uint2 pk;
        pk.x = pack_bf16(e0, e1);
        pk.y = pack_bf16(e2, e3);
        *(uint2*)(pw + qt * 16 * 72 + kb * 16) = pk;
      }
    }
    v8s pf[4];
#pragma unroll
    for (int s = 0; s < 4; ++s) pf[s] = *(const v8s*)(pr + s * 16);
#pragma unroll
    for (int t = 0; t < 4; ++t)
#pragma unroll
      for (int s = 0; s < 4; ++s)
        acc[t] = __builtin_amdgcn_mfma_f32_32x32x16_bf16(vf[t * 4 + s], pf[s], acc[t], 0, 0, 0);
#pragma unroll
    for (int kb = 0; kb < 4; ++kb) kf[kb] = kn[kb];
  }
}

// merge the two key-halves; afterwards ks==0 waves hold full O, lfq = denom for q=lane&31
__device__ __forceinline__ void merge_ks(
    v16f acc[4], float lsum[2], float* mergeO, float (*lbuf)[32],
    int ks, int chh, int lane, float& lfq) {
  float l0 = lsum[0] + __shfl_xor(lsum[0], 16); l0 += __shfl_xor(l0, 32);
  float l1 = lsum[1] + __shfl_xor(lsum[1], 16); l1 += __shfl_xor(l1, 32);
  if (chh == 0 && lane < 16) { lbuf[ks][lane] = l0; lbuf[ks][lane + 16] = l1; }
  __syncthreads();  // also: all P reads done before mergeO overwrites P area
  const int l31 = lane & 31, lh = lane >> 5;
  lfq = lbuf[0][l31] + lbuf[1][l31];
  if (ks == 1) {
    float* mo = mergeO + chh * (128 * 33);
#pragma unroll
    for (int t = 0; t < 4; ++t)
#pragma unroll
      for (int r = 0; r < 16; ++r) {
        int cl = (r & 3) + 8 * (r >> 2) + 4 * lh;
        mo[(t * 32 + cl) * 33 + l31] = acc[t][r];
      }
  }
  __syncthreads();
  if (ks == 0) {
    const float* mo = mergeO + chh * (128 * 33);
#pragma unroll
    for (int t = 0; t < 4; ++t)
#pragma unroll
      for (int r = 0; r < 16; ++r) {
        int cl = (r & 3) + 8 * (r >> 2) + 4 * lh;
        acc[t][r] += mo[(t * 32 + cl) * 33 + l31];
      }
  }
}

__global__ __launch_bounds__(256, 2) void fused_attn_kernel(
    const unsigned short* __restrict__ Q1g, const unsigned short* __restrict__ K1g,
    const unsigned short* __restrict__ V1g, const unsigned short* __restrict__ K2g,
    const unsigned short* __restrict__ V2g, const unsigned short* __restrict__ W2g,
    const float* __restrict__ x, const float* __restrict__ q2b,
    const float* __restrict__ g1p, const float* __restrict__ g2p,
    float* __restrict__ outp) {
  __shared__ __align__(16) char uarea[33792];  // P: 4 waves x 4608B (18.4KB) / mergeO 33.8KB
  __shared__ __align__(16) unsigned short out1T[32 * 264];  // out1 [q][c], stride 264
  __shared__ __align__(16) unsigned short q2s[32 * 32];     // q2 [q][o]
  __shared__ float lbuf[2][32];

  const int tid = threadIdx.x;
  const int lane = tid & 63;
  const int w = tid >> 6;
  const int ks = w >> 1;
  const int chh = w & 1;
  const int quad = lane >> 4;
  const int r15 = lane & 15;
  const int l31 = lane & 31, lh = lane >> 5;
  const int b = blockIdx.x & 3;  // XCD-friendly: batch -> L2 locality
  const int n0 = (blockIdx.x >> 2) * 32;

  unsigned short* Pl = (unsigned short*)uarea + w * 2304;
  float* mergeO = (float*)uarea;

  const float g1 = g1p[0];
  const float g2 = g2p[0];

  const unsigned short* Qp  = Q1g + (size_t)b * NSEQ * CQKD;
  const unsigned short* K1p = K1g + (size_t)b * NSEQ * CQKD;
  const unsigned short* K2p = K2g + (size_t)b * NSEQ * CQKD;
  const unsigned short* V1p = V1g + (size_t)b * CDIM * NSEQ;
  const unsigned short* V2p = V2g + (size_t)b * CDIM * NSEQ;

  v8s qf0 = *(const v8s*)(Qp + (n0 + r15) * CQKD + quad * 8);
  v8s qf1 = *(const v8s*)(Qp + (n0 + 16 + r15) * CQKD + quad * 8);

  v16f acc[4];
  float lsum[2] = {0.f, 0.f};
  float lfq;
#pragma unroll
  for (int t = 0; t < 4; ++t) acc[t] = (v16f)(0.f);

  // ---- layer 1 ----
  attn_loop(K1p, V1p, Pl, qf0, qf1, ks, chh, lane, acc, lsum);
  merge_ks(acc, lsum, mergeO, lbuf, ks, chh, lane, lfq);
  if (ks == 0) {
    const float rinv = 1.0f / lfq;
#pragma unroll
    for (int t = 0; t < 4; ++t)
#pragma unroll
      for (int rg = 0; rg < 4; ++rg) {
        const int c = chh * 128 + t * 32 + 8 * rg + 4 * lh;
        float o0 = g1 * (acc[t][rg * 4 + 0] * rinv) + x[((size_t)b * CDIM + c + 0) * NSEQ + n0 + l31];
        float o1 = g1 * (acc[t][rg * 4 + 1] * rinv) + x[((size_t)b * CDIM + c + 1) * NSEQ + n0 + l31];
        float o2 = g1 * (acc[t][rg * 4 + 2] * rinv) + x[((size_t)b * CDIM + c + 2) * NSEQ + n0 + l31];
        float o3 = g1 * (acc[t][rg * 4 + 3] * rinv) + x[((size_t)b * CDIM + c + 3) * NSEQ + n0 + l31];
        uint2 pk;
        pk.x = pack_bf16(o0, o1);
        pk.y = pack_bf16(o2, o3);
        *(uint2*)(out1T + l31 * 264 + c) = pk;
      }
  }
  __syncthreads();

  // ---- q2 projection (wave 0): q2[o][q] = W2[o][:] . out1[q][:] (W2 pre-scaled) ----
  if (w == 0) {
    v16f qacc = (v16f)(0.f);
#pragma unroll
    for (int s = 0; s < 16; ++s) {
      v8s af = *(const v8s*)(W2g + l31 * CDIM + s * 16 + lh * 8);
      v8s bf = *(const v8s*)(out1T + l31 * 264 + s * 16 + lh * 8);
      qacc = __builtin_amdgcn_mfma_f32_32x32x16_bf16(af, bf, qacc, 0, 0, 0);
    }
#pragma unroll
    for (int rg = 0; rg < 4; ++rg) {
      const int o = 8 * rg + 4 * lh;
      uint2 pk;
      pk.x = pack_bf16(qacc[rg * 4 + 0] + q2b[o + 0] * LOG2E, qacc[rg * 4 + 1] + q2b[o + 1] * LOG2E);
      pk.y = pack_bf16(qacc[rg * 4 + 2] + q2b[o + 2] * LOG2E, qacc[rg * 4 + 3] + q2b[o + 3] * LOG2E);
      *(uint2*)(q2s + l31 * 32 + o) = pk;
    }
  }
  __syncthreads();

  // ---- layer 2 ----
  qf0 = *(const v8s*)(q2s + r15 * 32 + quad * 8);
  qf1 = *(const v8s*)(q2s + (16 + r15) * 32 + quad * 8);
#pragma unroll
  for (int t = 0; t < 4; ++t) acc[t] = (v16f)(0.f);
  lsum[0] = 0.f; lsum[1] = 0.f;
  attn_loop(K2p, V2p, Pl, qf0, qf1, ks, chh, lane, acc, lsum);
  merge_ks(acc, lsum, mergeO, lbuf, ks, chh, lane, lfq);
  if (ks == 0) {
    const float rinv = 1.0f / lfq;
#pragma unroll
    for (int t = 0; t < 4; ++t)
#pragma unroll
      for (int rg = 0; rg < 4; ++rg) {
        const int c = chh * 128 + t * 32 + 8 * rg + 4 * lh;
#pragma unroll
        for (int i = 0; i < 4; ++i) {
          float res = bf2f(out1T[l31 * 264 + c + i]);
          outp[((size_t)b * CDIM + c + i) * NSEQ + n0 + l31] =
              g2 * (acc[t][rg * 4 + i] * rinv) + res;
        }
      }
  }
}

extern "C" void kernel_launch(void* const* d_in, const int* in_sizes, int n_in,
                              void* d_out, int out_size, void* d_ws, size_t ws_size,
                              hipStream_t stream) {
  const float* x   = (const float*)d_in[0];
  const float* y   = (const float*)d_in[1];
  const float* z   = (const float*)d_in[2];
  const float* q1w = (const float*)d_in[3];
  const float* q1b = (const float*)d_in[4];
  const float* k1w = (const float*)d_in[5];
  const float* k1b = (const float*)d_in[6];
  const float* v1w = (const float*)d_in[7];
  const float* v1b = (const float*)d_in[8];
  const float* g1  = (const float*)d_in[9];
  const float* q2w = (const float*)d_in[10];
  const float* q2b = (const float*)d_in[11];
  const float* k2w = (const float*)d_in[12];
  const float* k2b = (const float*)d_in[13];
  const float* v2w = (const float*)d_in[14];
  const float* v2b = (const float*)d_in[15];
  const float* g2  = (const float*)d_in[16];
  char* ws = (char*)d_ws;
  unsigned short* inT = (unsigned short*)(ws);                    // 25,165,824 B
  unsigned short* Wbf = (unsigned short*)(ws + 25165824);         // 327,680 B
  unsigned short* Q1  = (unsigned short*)(ws + 25493504);
  unsigned short* K1  = (unsigned short*)(ws + 26542080);
  unsigned short* K2  = (unsigned short*)(ws + 27590656);
  unsigned short* V1  = (unsigned short*)(ws + 28639232);
  unsigned short* V2  = (unsigned short*)(ws + 37027840);
  float* outp = (float*)d_out;

  convw_kernel<<<dim3(640), 256, 0, stream>>>(q1w, k1w, k2w, q2w, v1w, v2w, Wbf);
  transpose_kernel<<<dim3(64, 16, 3), 256, 0, stream>>>(x, y, z, inT);
  proj_qk_mfma<<<dim3(64, 4, 3), 256, 0, stream>>>(inT, Wbf, q1b, k1b, k2b, Q1, K1, K2);
  proj_v_mfma<<<dim3(64, 4, 2), 256, 0, stream>>>(inT, Wbf, v1b, v2b, V1, V2);
  fused_attn_kernel<<<dim3(512), 256, 0, stream>>>(Q1, K1, V1, K2, V2, Wbf + 24576, x,
                                                   q2b, g1, g2, outp);
}

// Round 6
// 311.274 us; speedup vs baseline: 2.1859x; 1.4023x over previous
//
#include <hip/hip_runtime.h>
#include <hip/hip_bf16.h>

#define NSEQ 4096
#define CDIM 256
#define CQKD 32
#define LOG2E 1.4426950408889634f

typedef float v4f __attribute__((ext_vector_type(4)));
typedef float v16f __attribute__((ext_vector_type(16)));
typedef short v8s __attribute__((ext_vector_type(8)));

__device__ __forceinline__ float exp2_(float x) { return exp2f(x); }

__device__ __forceinline__ unsigned short f2bf(float x) {
  unsigned u = __builtin_bit_cast(unsigned, x);
  unsigned r = (u + 0x7FFFu + ((u >> 16) & 1u)) >> 16;
  return (unsigned short)r;
}
__device__ __forceinline__ float bf2f(unsigned short s) {
  unsigned u = ((unsigned)s) << 16;
  return __builtin_bit_cast(float, u);
}
__device__ __forceinline__ unsigned int pack_bf16(float a, float b) {
#if __has_builtin(__builtin_amdgcn_cvt_pk_bf16_f32)
  typedef __bf16 v2bf __attribute__((ext_vector_type(2)));
  v2bf r = __builtin_amdgcn_cvt_pk_bf16_f32(a, b);
  return __builtin_bit_cast(unsigned int, r);
#else
  return ((unsigned)f2bf(b) << 16) | (unsigned)f2bf(a);
#endif
}

// ---------------- weight convert (bf16; q2 pre-scaled by log2e) ----------------
__global__ __launch_bounds__(256) void convw_kernel(
    const float* __restrict__ q1w, const float* __restrict__ k1w,
    const float* __restrict__ k2w, const float* __restrict__ q2w,
    const float* __restrict__ v1w, const float* __restrict__ v2w,
    unsigned short* __restrict__ W) {
  int i = blockIdx.x * 256 + threadIdx.x;
  float v;
  if (i < 8192) v = q1w[i];
  else if (i < 16384) v = k1w[i - 8192];
  else if (i < 24576) v = k2w[i - 16384];
  else if (i < 32768) v = q2w[i - 24576] * LOG2E;
  else if (i < 98304) v = v1w[i - 32768];
  else v = v2w[i - 98304];
  W[i] = f2bf(v);
}

// ---------------- transpose+convert: [b][ch][n] fp32 -> [src][b][n][ch] bf16 ----------------
__global__ __launch_bounds__(256) void transpose_kernel(
    const float* __restrict__ x, const float* __restrict__ y,
    const float* __restrict__ z, unsigned short* __restrict__ inT) {
  __shared__ unsigned short t[64][73];
  const int src = blockIdx.z;
  const float* in = src == 0 ? x : (src == 1 ? y : z);
  const int b = blockIdx.y & 3, cht = blockIdx.y >> 2;
  const int n0 = blockIdx.x * 64, ch0 = cht * 64;
  const int tid = threadIdx.x;
  const float* ip = in + ((size_t)(b * CDIM + ch0)) * NSEQ + n0;
#pragma unroll
  for (int r = 0; r < 16; ++r) {
    int ch = r * 4 + (tid >> 6);
    int n = tid & 63;
    t[ch][n] = f2bf(ip[(size_t)ch * NSEQ + n]);
  }
  __syncthreads();
  unsigned short* op = inT + ((size_t)src * 4 + b) * NSEQ * CDIM + (size_t)n0 * CDIM + ch0;
#pragma unroll
  for (int r = 0; r < 8; ++r) {
    int n = r * 8 + (tid >> 5);
    int cp = tid & 31;
    unsigned int v = ((unsigned)t[cp * 2 + 1][n] << 16) | t[cp * 2][n];
    *(unsigned int*)(op + (size_t)n * CDIM + cp * 2) = v;
  }
}

// ---------------- proj Q/K: Q row-major, K packed into 16x16x32 A-frag tiles ----------------
// Kp[b][kt16][lane][j]: elem j of lane = K[kt16*16 + (lane&15)][(lane>>4)*8 + j]
__global__ __launch_bounds__(256) void proj_qk_mfma(
    const unsigned short* __restrict__ inT, const unsigned short* __restrict__ Wbf,
    const float* __restrict__ q1b, const float* __restrict__ k1b,
    const float* __restrict__ k2b, unsigned short* __restrict__ Q1,
    unsigned short* __restrict__ K1, unsigned short* __restrict__ K2) {
  __shared__ unsigned short Kt[64][40];
  const int which = blockIdx.z;
  const unsigned short* Wp = Wbf + which * 8192;
  const float* bias = which == 0 ? q1b : (which == 1 ? k1b : k2b);
  const int b = blockIdx.y;
  const int lane = threadIdx.x & 63, w = threadIdx.x >> 6;
  const int quad = lane >> 4, r15 = lane & 15;
  const int n0 = blockIdx.x * 64 + w * 16;
  const unsigned short* ip = inT + ((size_t)which * 4 + b) * NSEQ * CDIM;
  v4f acc[2];
  const v4f vzero = {0.f, 0.f, 0.f, 0.f};
  acc[0] = vzero; acc[1] = vzero;
#pragma unroll
  for (int cb = 0; cb < 8; ++cb) {
    v8s af = *(const v8s*)(ip + (size_t)(n0 + r15) * CDIM + cb * 32 + quad * 8);
    v8s b0 = *(const v8s*)(Wp + (0 * 16 + r15) * CDIM + cb * 32 + quad * 8);
    v8s b1 = *(const v8s*)(Wp + (1 * 16 + r15) * CDIM + cb * 32 + quad * 8);
    acc[0] = __builtin_amdgcn_mfma_f32_16x16x32_bf16(af, b0, acc[0], 0, 0, 0);
    acc[1] = __builtin_amdgcn_mfma_f32_16x16x32_bf16(af, b1, acc[1], 0, 0, 0);
  }
  if (which == 0) {
#pragma unroll
    for (int ot = 0; ot < 2; ++ot) {
      const float bv = bias[ot * 16 + r15];
#pragma unroll
      for (int r = 0; r < 4; ++r)
        Q1[((size_t)b * NSEQ + n0 + quad * 4 + r) * CQKD + ot * 16 + r15] =
            f2bf((acc[ot][r] + bv) * LOG2E);
    }
  } else {
    unsigned short* out = (which == 1 ? K1 : K2) + (size_t)b * (NSEQ / 16) * 512;
#pragma unroll
    for (int ot = 0; ot < 2; ++ot) {
      const float bv = bias[ot * 16 + r15];
#pragma unroll
      for (int r = 0; r < 4; ++r)
        Kt[w * 16 + quad * 4 + r][ot * 16 + r15] = f2bf(acc[ot][r] + bv);
    }
    __syncthreads();
    union { uint2 u2[2]; v8s v; } u;
    u.u2[0] = *(const uint2*)&Kt[w * 16 + r15][quad * 8];
    u.u2[1] = *(const uint2*)&Kt[w * 16 + r15][quad * 8 + 4];
    *(v8s*)(out + (((size_t)blockIdx.x * 4 + w) * 64 + lane) * 8) = u.v;
  }
}

// ---------------- proj V: packed into 32x32x16 A-frag tiles ----------------
// Vp[b][kt16][chb][lane][j]: elem j = V[chb*32 + (lane&31)][kt16*16 + (lane>>5)*8 + j]
__global__ __launch_bounds__(256, 2) void proj_v_mfma(
    const unsigned short* __restrict__ inT, const unsigned short* __restrict__ Wbf,
    const float* __restrict__ v1b, const float* __restrict__ v2b,
    unsigned short* __restrict__ V1, unsigned short* __restrict__ V2) {
  __shared__ unsigned short Vt[256][72];  // [ch][key_local], 36 KB
  const int which = blockIdx.z;
  const unsigned short* Wp = Wbf + 32768 + which * 65536;
  const float* bias = which == 0 ? v1b : v2b;
  const int b = blockIdx.y;
  unsigned short* out = (which == 0 ? V1 : V2) + (size_t)b * (NSEQ / 16) * 8 * 512;
  const unsigned short* ip = inT + ((size_t)(which + 1) * 4 + b) * NSEQ * CDIM;
  const int lane = threadIdx.x & 63, w = threadIdx.x >> 6;
  const int quad = lane >> 4, r15 = lane & 15;
  const int l31 = lane & 31, lh = lane >> 5;
  const int n0 = blockIdx.x * 64 + w * 16;
  v4f acc[16];
  const v4f vzero = {0.f, 0.f, 0.f, 0.f};
#pragma unroll
  for (int ot = 0; ot < 16; ++ot) acc[ot] = vzero;
#pragma unroll
  for (int cb = 0; cb < 8; ++cb) {
    v8s af = *(const v8s*)(ip + (size_t)(n0 + r15) * CDIM + cb * 32 + quad * 8);
#pragma unroll
    for (int ot = 0; ot < 16; ++ot) {
      v8s bf = *(const v8s*)(Wp + (ot * 16 + r15) * CDIM + cb * 32 + quad * 8);
      acc[ot] = __builtin_amdgcn_mfma_f32_16x16x32_bf16(af, bf, acc[ot], 0, 0, 0);
    }
  }
#pragma unroll
  for (int ot = 0; ot < 16; ++ot) {
    const int ch = ot * 16 + r15;
    const float bv = bias[ch];
    uint2 pk;
    pk.x = pack_bf16(acc[ot][0] + bv, acc[ot][1] + bv);
    pk.y = pack_bf16(acc[ot][2] + bv, acc[ot][3] + bv);
    *(uint2*)&Vt[ch][w * 16 + quad * 4] = pk;
  }
  __syncthreads();
  const size_t ktb = (size_t)blockIdx.x * 4 + w;
#pragma unroll
  for (int chb = 0; chb < 8; ++chb) {
    union { uint2 u2[2]; v8s v; } u;
    u.u2[0] = *(const uint2*)&Vt[chb * 32 + l31][w * 16 + lh * 8];
    u.u2[1] = *(const uint2*)&Vt[chb * 32 + l31][w * 16 + lh * 8 + 4];
    *(v8s*)(out + ((ktb * 8 + chb) * 64 + lane) * 8) = u.v;
  }
}

// ---------------- fused double attention ----------------
// 256 threads = 4 waves: ks = w>>1 (key half), chh = w&1 (channel half). 32 q/block.
// K/V pre-packed in MFMA A-frag order: every hot load is base + tile*1KB + lane*16B.
__device__ __forceinline__ void attn_loop(
    const unsigned short* __restrict__ Kp, const unsigned short* __restrict__ Vp,
    unsigned short* Pl, const v8s qf0, const v8s qf1, int ks, int chh, int lane,
    v16f acc[4], float lsum[2]) {
  const v4f vzero4 = {0.f, 0.f, 0.f, 0.f};
  const int quad = (lane >> 4) & 3, r15 = lane & 15;
  const int l31 = lane & 31, lh = lane >> 5;
  unsigned short* pw = Pl + r15 * 72 + quad * 4;
  const unsigned short* pr = Pl + l31 * 72 + lh * 8;
  const int kt0base = ks * 128;  // 16-key tile index base
  const unsigned short* Kl = Kp + (size_t)lane * 8;
  const unsigned short* Vl = Vp + (size_t)lane * 8 + (size_t)chh * 4 * 512;
  v8s kf[4], kn[4];
#pragma unroll
  for (int kb = 0; kb < 4; ++kb)
    kf[kb] = *(const v8s*)(Kl + (size_t)(kt0base + kb) * 512);
  for (int kt = 0; kt < 32; ++kt) {
    const int t4 = kt0base + kt * 4;
    // V fragments for this 64-key tile: 16 coalesced 1KB loads, in flight across S phase
    v8s vf[16];
#pragma unroll
    for (int t = 0; t < 4; ++t)
#pragma unroll
      for (int s = 0; s < 4; ++s)
        vf[t * 4 + s] = *(const v8s*)(Vl + ((size_t)(t4 + s) * 8 + t) * 512);
    // prefetch next K tile
    const int tn4 = kt0base + ((kt + 1) & 31) * 4;
#pragma unroll
    for (int kb = 0; kb < 4; ++kb)
      kn[kb] = *(const v8s*)(Kl + (size_t)(tn4 + kb) * 512);
    // S^T = K.Q^T, exp2, pack to P[q][key]
#pragma unroll
    for (int qt = 0; qt < 2; ++qt) {
      const v8s qf = qt ? qf1 : qf0;
#pragma unroll
      for (int kb = 0; kb < 4; ++kb) {
        v4f st = __builtin_amdgcn_mfma_f32_16x16x32_bf16(kf[kb], qf, vzero4, 0, 0, 0);
        float e0 = exp2_(st[0]), e1 = exp2_(st[1]), e2 = exp2_(st[2]), e3 = exp2_(st[3]);
        lsum[qt] += (e0 + e1) + (e2 + e3);
        uint2 pk;
        pk.x = pack_bf16(e0, e1);
        pk.y = pack_bf16(e2, e3);
        *(uint2*)(pw + qt * 16 * 72 + kb * 16) = pk;
      }
    }
    v8s pf[4];
#pragma unroll
    for (int s = 0; s < 4; ++s) pf[s] = *(const v8s*)(pr + s * 16);
#pragma unroll
    for (int t = 0; t < 4; ++t)
#pragma unroll
      for (int s = 0; s < 4; ++s)
        acc[t] = __builtin_amdgcn_mfma_f32_32x32x16_bf16(vf[t * 4 + s], pf[s], acc[t], 0, 0, 0);
#pragma unroll
    for (int kb = 0; kb < 4; ++kb) kf[kb] = kn[kb];
  }
}

// merge the two key-halves; afterwards ks==0 waves hold full O, lfq = denom for q=lane&31
__device__ __forceinline__ void merge_ks(
    v16f acc[4], float lsum[2], float* mergeO, float (*lbuf)[32],
    int ks, int chh, int lane, float& lfq) {
  float l0 = lsum[0] + __shfl_xor(lsum[0], 16); l0 += __shfl_xor(l0, 32);
  float l1 = lsum[1] + __shfl_xor(lsum[1], 16); l1 += __shfl_xor(l1, 32);
  if (chh == 0 && lane < 16) { lbuf[ks][lane] = l0; lbuf[ks][lane + 16] = l1; }
  __syncthreads();  // also: all P reads done before mergeO overwrites P area
  const int l31 = lane & 31, lh = lane >> 5;
  lfq = lbuf[0][l31] + lbuf[1][l31];
  if (ks == 1) {
    float* mo = mergeO + chh * (128 * 33);
#pragma unroll
    for (int t = 0; t < 4; ++t)
#pragma unroll
      for (int r = 0; r < 16; ++r) {
        int cl = (r & 3) + 8 * (r >> 2) + 4 * lh;
        mo[(t * 32 + cl) * 33 + l31] = acc[t][r];
      }
  }
  __syncthreads();
  if (ks == 0) {
    const float* mo = mergeO + chh * (128 * 33);
#pragma unroll
    for (int t = 0; t < 4; ++t)
#pragma unroll
      for (int r = 0; r < 16; ++r) {
        int cl = (r & 3) + 8 * (r >> 2) + 4 * lh;
        acc[t][r] += mo[(t * 32 + cl) * 33 + l31];
      }
  }
}

__global__ __launch_bounds__(256, 2) void fused_attn_kernel(
    const unsigned short* __restrict__ Q1g, const unsigned short* __restrict__ K1g,
    const unsigned short* __restrict__ V1g, const unsigned short* __restrict__ K2g,
    const unsigned short* __restrict__ V2g, const unsigned short* __restrict__ W2g,
    const float* __restrict__ x, const float* __restrict__ q2b,
    const float* __restrict__ g1p, const float* __restrict__ g2p,
    float* __restrict__ outp) {
  __shared__ __align__(16) char uarea[33792];  // P: 4 waves x 4608B / mergeO 33.8KB
  __shared__ __align__(16) unsigned short out1T[32 * 264];  // out1 [q][c], stride 264
  __shared__ __align__(16) unsigned short q2s[32 * 32];     // q2 [q][o]
  __shared__ float lbuf[2][32];

  const int tid = threadIdx.x;
  const int lane = tid & 63;
  const int w = tid >> 6;
  const int ks = w >> 1;
  const int chh = w & 1;
  const int quad = lane >> 4;
  const int r15 = lane & 15;
  const int l31 = lane & 31, lh = lane >> 5;
  const int b = blockIdx.x & 3;  // XCD-friendly: batch -> L2 locality
  const int n0 = (blockIdx.x >> 2) * 32;

  unsigned short* Pl = (unsigned short*)uarea + w * 2304;
  float* mergeO = (float*)uarea;

  const float g1 = g1p[0];
  const float g2 = g2p[0];

  const unsigned short* Qp  = Q1g + (size_t)b * NSEQ * CQKD;
  const unsigned short* K1p = K1g + (size_t)b * (NSEQ / 16) * 512;
  const unsigned short* K2p = K2g + (size_t)b * (NSEQ / 16) * 512;
  const unsigned short* V1p = V1g + (size_t)b * (NSEQ / 16) * 8 * 512;
  const unsigned short* V2p = V2g + (size_t)b * (NSEQ / 16) * 8 * 512;

  v8s qf0 = *(const v8s*)(Qp + (n0 + r15) * CQKD + quad * 8);
  v8s qf1 = *(const v8s*)(Qp + (n0 + 16 + r15) * CQKD + quad * 8);

  v16f acc[4];
  float lsum[2] = {0.f, 0.f};
  float lfq;
#pragma unroll
  for (int t = 0; t < 4; ++t) acc[t] = (v16f)(0.f);

  // ---- layer 1 ----
  attn_loop(K1p, V1p, Pl, qf0, qf1, ks, chh, lane, acc, lsum);
  merge_ks(acc, lsum, mergeO, lbuf, ks, chh, lane, lfq);
  if (ks == 0) {
    const float rinv = 1.0f / lfq;
#pragma unroll
    for (int t = 0; t < 4; ++t)
#pragma unroll
      for (int rg = 0; rg < 4; ++rg) {
        const int c = chh * 128 + t * 32 + 8 * rg + 4 * lh;
        float o0 = g1 * (acc[t][rg * 4 + 0] * rinv) + x[((size_t)b * CDIM + c + 0) * NSEQ + n0 + l31];
        float o1 = g1 * (acc[t][rg * 4 + 1] * rinv) + x[((size_t)b * CDIM + c + 1) * NSEQ + n0 + l31];
        float o2 = g1 * (acc[t][rg * 4 + 2] * rinv) + x[((size_t)b * CDIM + c + 2) * NSEQ + n0 + l31];
        float o3 = g1 * (acc[t][rg * 4 + 3] * rinv) + x[((size_t)b * CDIM + c + 3) * NSEQ + n0 + l31];
        uint2 pk;
        pk.x = pack_bf16(o0, o1);
        pk.y = pack_bf16(o2, o3);
        *(uint2*)(out1T + l31 * 264 + c) = pk;
      }
  }
  __syncthreads();

  // ---- q2 projection (wave 0): q2[o][q] = W2[o][:] . out1[q][:] (W2 pre-scaled) ----
  if (w == 0) {
    v16f qacc = (v16f)(0.f);
#pragma unroll
    for (int s = 0; s < 16; ++s) {
      v8s af = *(const v8s*)(W2g + l31 * CDIM + s * 16 + lh * 8);
      v8s bf = *(const v8s*)(out1T + l31 * 264 + s * 16 + lh * 8);
      qacc = __builtin_amdgcn_mfma_f32_32x32x16_bf16(af, bf, qacc, 0, 0, 0);
    }
#pragma unroll
    for (int rg = 0; rg < 4; ++rg) {
      const int o = 8 * rg + 4 * lh;
      uint2 pk;
      pk.x = pack_bf16(qacc[rg * 4 + 0] + q2b[o + 0] * LOG2E, qacc[rg * 4 + 1] + q2b[o + 1] * LOG2E);
      pk.y = pack_bf16(qacc[rg * 4 + 2] + q2b[o + 2] * LOG2E, qacc[rg * 4 + 3] + q2b[o + 3] * LOG2E);
      *(uint2*)(q2s + l31 * 32 + o) = pk;
    }
  }
  __syncthreads();

  // ---- layer 2 ----
  qf0 = *(const v8s*)(q2s + r15 * 32 + quad * 8);
  qf1 = *(const v8s*)(q2s + (16 + r15) * 32 + quad * 8);
#pragma unroll
  for (int t = 0; t < 4; ++t) acc[t] = (v16f)(0.f);
  lsum[0] = 0.f; lsum[1] = 0.f;
  attn_loop(K2p, V2p, Pl, qf0, qf1, ks, chh, lane, acc, lsum);
  merge_ks(acc, lsum, mergeO, lbuf, ks, chh, lane, lfq);
  if (ks == 0) {
    const float rinv = 1.0f / lfq;
#pragma unroll
    for (int t = 0; t < 4; ++t)
#pragma unroll
      for (int rg = 0; rg < 4; ++rg) {
        const int c = chh * 128 + t * 32 + 8 * rg + 4 * lh;
#pragma unroll
        for (int i = 0; i < 4; ++i) {
          float res = bf2f(out1T[l31 * 264 + c + i]);
          outp[((size_t)b * CDIM + c + i) * NSEQ + n0 + l31] =
              g2 * (acc[t][rg * 4 + i] * rinv) + res;
        }
      }
  }
}

extern "C" void kernel_launch(void* const* d_in, const int* in_sizes, int n_in,
                              void* d_out, int out_size, void* d_ws, size_t ws_size,
                              hipStream_t stream) {
  const float* x   = (const float*)d_in[0];
  const float* y   = (const float*)d_in[1];
  const float* z   = (const float*)d_in[2];
  const float* q1w = (const float*)d_in[3];
  const float* q1b = (const float*)d_in[4];
  const float* k1w = (const float*)d_in[5];
  const float* k1b = (const float*)d_in[6];
  const float* v1w = (const float*)d_in[7];
  const float* v1b = (const float*)d_in[8];
  const float* g1  = (const float*)d_in[9];
  const float* q2w = (const float*)d_in[10];
  const float* q2b = (const float*)d_in[11];
  const float* k2w = (const float*)d_in[12];
  const float* k2b = (const float*)d_in[13];
  const float* v2w = (const float*)d_in[14];
  const float* v2b = (const float*)d_in[15];
  const float* g2  = (const float*)d_in[16];
  char* ws = (char*)d_ws;
  unsigned short* inT = (unsigned short*)(ws);                    // 25,165,824 B
  unsigned short* Wbf = (unsigned short*)(ws + 25165824);         // 327,680 B
  unsigned short* Q1  = (unsigned short*)(ws + 25493504);         // 1 MB (row-major)
  unsigned short* K1  = (unsigned short*)(ws + 26542080);         // 1 MB (packed)
  unsigned short* K2  = (unsigned short*)(ws + 27590656);         // 1 MB (packed)
  unsigned short* V1  = (unsigned short*)(ws + 28639232);         // 8 MB (packed)
  unsigned short* V2  = (unsigned short*)(ws + 37027840);         // 8 MB (packed)
  float* outp = (float*)d_out;

  convw_kernel<<<dim3(640), 256, 0, stream>>>(q1w, k1w, k2w, q2w, v1w, v2w, Wbf);
  transpose_kernel<<<dim3(64, 16, 3), 256, 0, stream>>>(x, y, z, inT);
  proj_qk_mfma<<<dim3(64, 4, 3), 256, 0, stream>>>(inT, Wbf, q1b, k1b, k2b, Q1, K1, K2);
  proj_v_mfma<<<dim3(64, 4, 2), 256, 0, stream>>>(inT, Wbf, v1b, v2b, V1, V2);
  fused_attn_kernel<<<dim3(512), 256, 0, stream>>>(Q1, K1, V1, K2, V2, Wbf + 24576, x,
                                                   q2b, g1, g2, outp);
}

// Round 7
// 277.770 us; speedup vs baseline: 2.4496x; 1.1206x over previous
//
#include <hip/hip_runtime.h>
#include <hip/hip_bf16.h>

#define NSEQ 4096
#define CDIM 256
#define CQKD 32
#define LOG2E 1.4426950408889634f

typedef float v4f __attribute__((ext_vector_type(4)));
typedef float v16f __attribute__((ext_vector_type(16)));
typedef short v8s __attribute__((ext_vector_type(8)));

__device__ __forceinline__ float exp2_(float x) { return exp2f(x); }

__device__ __forceinline__ unsigned short f2bf(float x) {
  unsigned u = __builtin_bit_cast(unsigned, x);
  unsigned r = (u + 0x7FFFu + ((u >> 16) & 1u)) >> 16;
  return (unsigned short)r;
}
__device__ __forceinline__ float bf2f(unsigned short s) {
  unsigned u = ((unsigned)s) << 16;
  return __builtin_bit_cast(float, u);
}
__device__ __forceinline__ unsigned int pack_bf16(float a, float b) {
#if __has_builtin(__builtin_amdgcn_cvt_pk_bf16_f32)
  typedef __bf16 v2bf __attribute__((ext_vector_type(2)));
  v2bf r = __builtin_amdgcn_cvt_pk_bf16_f32(a, b);
  return __builtin_bit_cast(unsigned int, r);
#else
  return ((unsigned)f2bf(b) << 16) | (unsigned)f2bf(a);
#endif
}

// ---------------- weight convert+frag-pack (bf16) ----------------
// Wbf (shorts): q1 @0, k1 @8192, k2 @16384 (B-frag 16x16x32, 2 ot x 8 cb)
//               q2 @24576 (A-frag 32x32x16, 16 slabs, pre-scaled log2e)
//               v1 @32768, v2 @98304 (B-frag 16x16x32, 16 ot x 8 cb)
// B-frag elem j of lane = W[o = ot*16 + (lane&15)][ch = cb*32 + (lane>>4)*8 + j]
// A32-frag elem j      = W[o = lane&31][ch = s*16 + (lane>>5)*8 + j]
__global__ __launch_bounds__(256) void convw_kernel(
    const float* __restrict__ q1w, const float* __restrict__ k1w,
    const float* __restrict__ k2w, const float* __restrict__ q2w,
    const float* __restrict__ v1w, const float* __restrict__ v2w,
    unsigned short* __restrict__ W) {
  const int s = blockIdx.x * 256 + threadIdx.x;  // v8s slot, 20480 total
  const float* src;
  int o, ch0;
  size_t obase;
  float scale = 1.0f;
  if (s < 3072) {
    const int wsel = s >> 10, r = s & 1023;
    src = wsel == 0 ? q1w : (wsel == 1 ? k1w : k2w);
    const int ot = r >> 9, cb = (r >> 6) & 7, lane = r & 63;
    o = ot * 16 + (lane & 15);
    ch0 = cb * 32 + ((lane >> 4) & 3) * 8;
    obase = (size_t)wsel * 8192 + (size_t)r * 8;
  } else if (s < 19456) {
    const int s2 = s - 3072, which = s2 >> 13, r = s2 & 8191;
    src = which == 0 ? v1w : v2w;
    const int ot = r >> 9, cb = (r >> 6) & 7, lane = r & 63;
    o = ot * 16 + (lane & 15);
    ch0 = cb * 32 + ((lane >> 4) & 3) * 8;
    obase = 32768 + (size_t)which * 65536 + (size_t)r * 8;
  } else {
    const int r = s - 19456;  // 0..1023
    src = q2w;
    const int lane = r & 63;
    o = lane & 31;
    ch0 = (r >> 6) * 16 + (lane >> 5) * 8;
    obase = 24576 + (size_t)r * 8;
    scale = LOG2E;
  }
#pragma unroll
  for (int j = 0; j < 8; ++j)
    W[obase + j] = f2bf(src[o * CDIM + ch0 + j] * scale);
}

// ---------------- transpose+convert: fp32 [b][ch][n] -> bf16 16x16x32-A-frag tiles ----
// inT[src][b][nt256][cb8][lane64][8]: elem j = in[n = nt*16+(lane&15)][ch = cb*32+(lane>>4)*8+j]
__global__ __launch_bounds__(256) void transpose_kernel(
    const float* __restrict__ x, const float* __restrict__ y,
    const float* __restrict__ z, unsigned short* __restrict__ inT) {
  __shared__ unsigned short t[64][73];  // [ch_local][n_local]
  const int src = blockIdx.z;
  const float* in = src == 0 ? x : (src == 1 ? y : z);
  const int b = blockIdx.y & 3, cht = blockIdx.y >> 2;
  const int n0 = blockIdx.x * 64, ch0 = cht * 64;
  const int tid = threadIdx.x;
  const float* ip = in + ((size_t)(b * CDIM + ch0)) * NSEQ + n0;
#pragma unroll
  for (int r = 0; r < 16; ++r) {
    int ch = r * 4 + (tid >> 6);
    int n = tid & 63;
    t[ch][n] = f2bf(ip[(size_t)ch * NSEQ + n]);
  }
  __syncthreads();
  // emit 8 frags (ntl 0..3 x cbl 0..1); 512 lane-slots, 2 per thread
  unsigned short* op = inT + ((((size_t)src * 4 + b) * 256) + (size_t)blockIdx.x * 4) * 4096 +
                       (size_t)cht * 2 * 512;
#pragma unroll
  for (int sIt = 0; sIt < 2; ++sIt) {
    const int slot = sIt * 256 + tid;
    const int lane = slot & 63, f = slot >> 6;
    const int ntl = f >> 1, cbl = f & 1;
    const int nl = ntl * 16 + (lane & 15);
    const int c0 = cbl * 32 + ((lane >> 4) & 3) * 8;
    union { unsigned short e[8]; v8s v; } u;
#pragma unroll
    for (int j = 0; j < 8; ++j) u.e[j] = t[c0 + j][nl];
    // offset: (ntl*4096? no) -> nt-tile stride = 8 cb * 512 = 4096; cb stride 512
    *(v8s*)(op + (size_t)ntl * 4096 + (size_t)cbl * 512 + lane * 8) = u.v;
  }
}

// ---------------- proj Q/K (frag-in, frag-out K; row-major Q) ----------------
__global__ __launch_bounds__(256) void proj_qk_mfma(
    const unsigned short* __restrict__ inT, const unsigned short* __restrict__ Wbf,
    const float* __restrict__ q1b, const float* __restrict__ k1b,
    const float* __restrict__ k2b, unsigned short* __restrict__ Q1,
    unsigned short* __restrict__ K1, unsigned short* __restrict__ K2) {
  __shared__ unsigned short Kt[64][40];
  const int which = blockIdx.z;
  const unsigned short* Wp = Wbf + which * 8192;
  const float* bias = which == 0 ? q1b : (which == 1 ? k1b : k2b);
  const int b = blockIdx.y;
  const int lane = threadIdx.x & 63, w = threadIdx.x >> 6;
  const int quad = lane >> 4, r15 = lane & 15;
  const int nt = blockIdx.x * 4 + w;
  const unsigned short* ip = inT + (((size_t)which * 4 + b) * 256 + nt) * 4096;
  v4f acc[2];
  const v4f vzero = {0.f, 0.f, 0.f, 0.f};
  acc[0] = vzero; acc[1] = vzero;
#pragma unroll
  for (int cb = 0; cb < 8; ++cb) {
    v8s af = *(const v8s*)(ip + cb * 512 + lane * 8);
    v8s b0 = *(const v8s*)(Wp + (0 * 8 + cb) * 512 + lane * 8);
    v8s b1 = *(const v8s*)(Wp + (1 * 8 + cb) * 512 + lane * 8);
    acc[0] = __builtin_amdgcn_mfma_f32_16x16x32_bf16(af, b0, acc[0], 0, 0, 0);
    acc[1] = __builtin_amdgcn_mfma_f32_16x16x32_bf16(af, b1, acc[1], 0, 0, 0);
  }
  const int n0 = nt * 16;
  if (which == 0) {
#pragma unroll
    for (int ot = 0; ot < 2; ++ot) {
      const float bv = bias[ot * 16 + r15];
#pragma unroll
      for (int r = 0; r < 4; ++r)
        Q1[((size_t)b * NSEQ + n0 + quad * 4 + r) * CQKD + ot * 16 + r15] =
            f2bf((acc[ot][r] + bv) * LOG2E);
    }
  } else {
    unsigned short* out = (which == 1 ? K1 : K2) + (size_t)b * (NSEQ / 16) * 512;
#pragma unroll
    for (int ot = 0; ot < 2; ++ot) {
      const float bv = bias[ot * 16 + r15];
#pragma unroll
      for (int r = 0; r < 4; ++r)
        Kt[w * 16 + quad * 4 + r][ot * 16 + r15] = f2bf(acc[ot][r] + bv);
    }
    __syncthreads();
    union { uint2 u2[2]; v8s v; } u;
    u.u2[0] = *(const uint2*)&Kt[w * 16 + r15][quad * 8];
    u.u2[1] = *(const uint2*)&Kt[w * 16 + r15][quad * 8 + 4];
    *(v8s*)(out + ((size_t)nt * 64 + lane) * 8) = u.v;
  }
}

// ---------------- proj V (frag-in, frag-out 32x32x16 A tiles) ----------------
__global__ __launch_bounds__(256, 2) void proj_v_mfma(
    const unsigned short* __restrict__ inT, const unsigned short* __restrict__ Wbf,
    const float* __restrict__ v1b, const float* __restrict__ v2b,
    unsigned short* __restrict__ V1, unsigned short* __restrict__ V2) {
  __shared__ unsigned short Vt[256][72];  // [ch][key_local]
  const int which = blockIdx.z;
  const unsigned short* Wp = Wbf + 32768 + which * 65536;
  const float* bias = which == 0 ? v1b : v2b;
  const int b = blockIdx.y;
  unsigned short* out = (which == 0 ? V1 : V2) + (size_t)b * (NSEQ / 16) * 8 * 512;
  const int lane = threadIdx.x & 63, w = threadIdx.x >> 6;
  const int quad = lane >> 4, r15 = lane & 15;
  const int l31 = lane & 31, lh = lane >> 5;
  const int nt = blockIdx.x * 4 + w;
  const unsigned short* ip = inT + (((size_t)(which + 1) * 4 + b) * 256 + nt) * 4096;
  v4f acc[16];
  const v4f vzero = {0.f, 0.f, 0.f, 0.f};
#pragma unroll
  for (int ot = 0; ot < 16; ++ot) acc[ot] = vzero;
#pragma unroll
  for (int cb = 0; cb < 8; ++cb) {
    v8s af = *(const v8s*)(ip + cb * 512 + lane * 8);
#pragma unroll
    for (int ot = 0; ot < 16; ++ot) {
      v8s bf = *(const v8s*)(Wp + ((size_t)(ot * 8 + cb)) * 512 + lane * 8);
      acc[ot] = __builtin_amdgcn_mfma_f32_16x16x32_bf16(af, bf, acc[ot], 0, 0, 0);
    }
  }
#pragma unroll
  for (int ot = 0; ot < 16; ++ot) {
    const int ch = ot * 16 + r15;
    const float bv = bias[ch];
    uint2 pk;
    pk.x = pack_bf16(acc[ot][0] + bv, acc[ot][1] + bv);
    pk.y = pack_bf16(acc[ot][2] + bv, acc[ot][3] + bv);
    *(uint2*)&Vt[ch][w * 16 + quad * 4] = pk;
  }
  __syncthreads();
#pragma unroll
  for (int chb = 0; chb < 8; ++chb) {
    union { uint2 u2[2]; v8s v; } u;
    u.u2[0] = *(const uint2*)&Vt[chb * 32 + l31][w * 16 + lh * 8];
    u.u2[1] = *(const uint2*)&Vt[chb * 32 + l31][w * 16 + lh * 8 + 4];
    *(v8s*)(out + (((size_t)nt * 8 + chb) * 64 + lane) * 8) = u.v;
  }
}

// ---------------- fused double attention ----------------
// 256 threads = 4 waves: ks = w>>1 (key half), chh = w&1 (channel half). 32 q/block.
// chh-pair SHARES the S phase: each wave computes 2 of 4 key-blocks' scores into a
// shared, double-buffered P region; per-tile __syncthreads; both read all 64 keys.
// V fragments prefetched one tile ahead to cover the shortened S phase.
__device__ __forceinline__ void attn_loop(
    const unsigned short* __restrict__ Kp, const unsigned short* __restrict__ Vp,
    unsigned short* Pks, const v8s qf0, const v8s qf1, int ks, int chh, int lane,
    v16f acc[4], float lsum[2]) {
  const v4f vzero4 = {0.f, 0.f, 0.f, 0.f};
  const int quad = (lane >> 4) & 3, r15 = lane & 15;
  const int l31 = lane & 31, lh = lane >> 5;
  const int kbA = chh * 2;
  const int kt0base = ks * 128;
  const unsigned short* Kl = Kp + (size_t)lane * 8;
  const unsigned short* Vl = Vp + (size_t)lane * 8 + (size_t)chh * 4 * 512;
  unsigned short* pwA = Pks + r15 * 72 + quad * 4 + kbA * 16;
  v8s kf0 = *(const v8s*)(Kl + (size_t)(kt0base + kbA) * 512);
  v8s kf1 = *(const v8s*)(Kl + (size_t)(kt0base + kbA + 1) * 512);
  v8s vf[16];
#pragma unroll
  for (int t = 0; t < 4; ++t)
#pragma unroll
    for (int s = 0; s < 4; ++s)
      vf[t * 4 + s] = *(const v8s*)(Vl + ((size_t)(kt0base + s) * 8 + t) * 512);
  for (int kt = 0; kt < 32; ++kt) {
    const int tn4 = kt0base + ((kt + 1) & 31) * 4;
    // prefetch next K pair + next V tile (consumed next iteration)
    v8s kn0 = *(const v8s*)(Kl + (size_t)(tn4 + kbA) * 512);
    v8s kn1 = *(const v8s*)(Kl + (size_t)(tn4 + kbA + 1) * 512);
    v8s vfn[16];
#pragma unroll
    for (int t = 0; t < 4; ++t)
#pragma unroll
      for (int s = 0; s < 4; ++s)
        vfn[t * 4 + s] = *(const v8s*)(Vl + ((size_t)(tn4 + s) * 8 + t) * 512);
    // S phase: own kb pair only (chh-shared)
    unsigned short* pw = pwA + (kt & 1) * 2304;
#pragma unroll
    for (int qt = 0; qt < 2; ++qt) {
      const v8s qf = qt ? qf1 : qf0;
#pragma unroll
      for (int kb = 0; kb < 2; ++kb) {
        v4f st = __builtin_amdgcn_mfma_f32_16x16x32_bf16(kb ? kf1 : kf0, qf, vzero4, 0, 0, 0);
        float e0 = exp2_(st[0]), e1 = exp2_(st[1]), e2 = exp2_(st[2]), e3 = exp2_(st[3]);
        lsum[qt] += (e0 + e1) + (e2 + e3);
        uint2 pk;
        pk.x = pack_bf16(e0, e1);
        pk.y = pack_bf16(e2, e3);
        *(uint2*)(pw + qt * 16 * 72 + kb * 16) = pk;
      }
    }
    __syncthreads();
    const unsigned short* pr = Pks + (kt & 1) * 2304 + l31 * 72 + lh * 8;
    v8s pf[4];
#pragma unroll
    for (int s = 0; s < 4; ++s) pf[s] = *(const v8s*)(pr + s * 16);
#pragma unroll
    for (int t = 0; t < 4; ++t)
#pragma unroll
      for (int s = 0; s < 4; ++s)
        acc[t] = __builtin_amdgcn_mfma_f32_32x32x16_bf16(vf[t * 4 + s], pf[s], acc[t], 0, 0, 0);
    kf0 = kn0; kf1 = kn1;
#pragma unroll
    for (int i = 0; i < 16; ++i) vf[i] = vfn[i];
  }
}

// merge key-halves; afterwards ks==0 waves hold full O, lfq = denom for q=lane&31
__device__ __forceinline__ void merge_ks(
    v16f acc[4], float lsum[2], float* mergeO, float (*lbuf)[32],
    int ks, int chh, int lane, float& lfq) {
  float l0 = lsum[0] + __shfl_xor(lsum[0], 16); l0 += __shfl_xor(l0, 32);
  float l1 = lsum[1] + __shfl_xor(lsum[1], 16); l1 += __shfl_xor(l1, 32);
  if (lane < 16) { lbuf[ks * 2 + chh][lane] = l0; lbuf[ks * 2 + chh][lane + 16] = l1; }
  __syncthreads();  // also: all P reads done before mergeO overwrites P area
  const int l31 = lane & 31, lh = lane >> 5;
  lfq = (lbuf[0][l31] + lbuf[1][l31]) + (lbuf[2][l31] + lbuf[3][l31]);
  if (ks == 1) {
    float* mo = mergeO + chh * (128 * 33);
#pragma unroll
    for (int t = 0; t < 4; ++t)
#pragma unroll
      for (int r = 0; r < 16; ++r) {
        int cl = (r & 3) + 8 * (r >> 2) + 4 * lh;
        mo[(t * 32 + cl) * 33 + l31] = acc[t][r];
      }
  }
  __syncthreads();
  if (ks == 0) {
    const float* mo = mergeO + chh * (128 * 33);
#pragma unroll
    for (int t = 0; t < 4; ++t)
#pragma unroll
      for (int r = 0; r < 16; ++r) {
        int cl = (r & 3) + 8 * (r >> 2) + 4 * lh;
        acc[t][r] += mo[(t * 32 + cl) * 33 + l31];
      }
  }
}

__global__ __launch_bounds__(256, 2) void fused_attn_kernel(
    const unsigned short* __restrict__ Q1g, const unsigned short* __restrict__ K1g,
    const unsigned short* __restrict__ V1g, const unsigned short* __restrict__ K2g,
    const unsigned short* __restrict__ V2g, const unsigned short* __restrict__ W2g,
    const float* __restrict__ x, const float* __restrict__ q2b,
    const float* __restrict__ g1p, const float* __restrict__ g2p,
    float* __restrict__ outp) {
  // P region: [ks][dbuf][32*72] shorts = 18432B, inside 33792B merge area
  __shared__ __align__(16) char uarea[33792];
  __shared__ __align__(16) unsigned short out1T[32 * 264];  // out1 [q][c]
  __shared__ __align__(16) unsigned short q2s[32 * 32];     // q2 [q][o]
  __shared__ float lbuf[4][32];

  const int tid = threadIdx.x;
  const int lane = tid & 63;
  const int w = tid >> 6;
  const int ks = w >> 1;
  const int chh = w & 1;
  const int quad = lane >> 4;
  const int r15 = lane & 15;
  const int l31 = lane & 31, lh = lane >> 5;
  const int b = blockIdx.x & 3;
  const int n0 = (blockIdx.x >> 2) * 32;

  unsigned short* Pks = (unsigned short*)uarea + ks * 2 * 2304;
  float* mergeO = (float*)uarea;

  const float g1 = g1p[0];
  const float g2 = g2p[0];

  const unsigned short* Qp  = Q1g + (size_t)b * NSEQ * CQKD;
  const unsigned short* K1p = K1g + (size_t)b * (NSEQ / 16) * 512;
  const unsigned short* K2p = K2g + (size_t)b * (NSEQ / 16) * 512;
  const unsigned short* V1p = V1g + (size_t)b * (NSEQ / 16) * 8 * 512;
  const unsigned short* V2p = V2g + (size_t)b * (NSEQ / 16) * 8 * 512;

  v8s qf0 = *(const v8s*)(Qp + (n0 + r15) * CQKD + quad * 8);
  v8s qf1 = *(const v8s*)(Qp + (n0 + 16 + r15) * CQKD + quad * 8);

  v16f acc[4];
  float lsum[2] = {0.f, 0.f};
  float lfq;
#pragma unroll
  for (int t = 0; t < 4; ++t) acc[t] = (v16f)(0.f);

  // ---- layer 1 ----
  attn_loop(K1p, V1p, Pks, qf0, qf1, ks, chh, lane, acc, lsum);
  merge_ks(acc, lsum, mergeO, lbuf, ks, chh, lane, lfq);
  if (ks == 0) {
    const float rinv = 1.0f / lfq;
#pragma unroll
    for (int t = 0; t < 4; ++t)
#pragma unroll
      for (int rg = 0; rg < 4; ++rg) {
        const int c = chh * 128 + t * 32 + 8 * rg + 4 * lh;
        float o0 = g1 * (acc[t][rg * 4 + 0] * rinv) + x[((size_t)b * CDIM + c + 0) * NSEQ + n0 + l31];
        float o1 = g1 * (acc[t][rg * 4 + 1] * rinv) + x[((size_t)b * CDIM + c + 1) * NSEQ + n0 + l31];
        float o2 = g1 * (acc[t][rg * 4 + 2] * rinv) + x[((size_t)b * CDIM + c + 2) * NSEQ + n0 + l31];
        float o3 = g1 * (acc[t][rg * 4 + 3] * rinv) + x[((size_t)b * CDIM + c + 3) * NSEQ + n0 + l31];
        uint2 pk;
        pk.x = pack_bf16(o0, o1);
        pk.y = pack_bf16(o2, o3);
        *(uint2*)(out1T + l31 * 264 + c) = pk;
      }
  }
  __syncthreads();

  // ---- q2 projection (wave 0): W2 pre-packed A-frag 32x32x16, pre-scaled ----
  if (w == 0) {
    v16f qacc = (v16f)(0.f);
#pragma unroll
    for (int s = 0; s < 16; ++s) {
      v8s af = *(const v8s*)(W2g + (s * 64 + lane) * 8);
      v8s bf = *(const v8s*)(out1T + l31 * 264 + s * 16 + lh * 8);
      qacc = __builtin_amdgcn_mfma_f32_32x32x16_bf16(af, bf, qacc, 0, 0, 0);
    }
#pragma unroll
    for (int rg = 0; rg < 4; ++rg) {
      const int o = 8 * rg + 4 * lh;
      uint2 pk;
      pk.x = pack_bf16(qacc[rg * 4 + 0] + q2b[o + 0] * LOG2E, qacc[rg * 4 + 1] + q2b[o + 1] * LOG2E);
      pk.y = pack_bf16(qacc[rg * 4 + 2] + q2b[o + 2] * LOG2E, qacc[rg * 4 + 3] + q2b[o + 3] * LOG2E);
      *(uint2*)(q2s + l31 * 32 + o) = pk;
    }
  }
  __syncthreads();

  // ---- layer 2 ----
  qf0 = *(const v8s*)(q2s + r15 * 32 + quad * 8);
  qf1 = *(const v8s*)(q2s + (16 + r15) * 32 + quad * 8);
#pragma unroll
  for (int t = 0; t < 4; ++t) acc[t] = (v16f)(0.f);
  lsum[0] = 0.f; lsum[1] = 0.f;
  attn_loop(K2p, V2p, Pks, qf0, qf1, ks, chh, lane, acc, lsum);
  merge_ks(acc, lsum, mergeO, lbuf, ks, chh, lane, lfq);
  if (ks == 0) {
    const float rinv = 1.0f / lfq;
#pragma unroll
    for (int t = 0; t < 4; ++t)
#pragma unroll
      for (int rg = 0; rg < 4; ++rg) {
        const int c = chh * 128 + t * 32 + 8 * rg + 4 * lh;
#pragma unroll
        for (int i = 0; i < 4; ++i) {
          float res = bf2f(out1T[l31 * 264 + c + i]);
          outp[((size_t)b * CDIM + c + i) * NSEQ + n0 + l31] =
              g2 * (acc[t][rg * 4 + i] * rinv) + res;
        }
      }
  }
}

extern "C" void kernel_launch(void* const* d_in, const int* in_sizes, int n_in,
                              void* d_out, int out_size, void* d_ws, size_t ws_size,
                              hipStream_t stream) {
  const float* x   = (const float*)d_in[0];
  const float* y   = (const float*)d_in[1];
  const float* z   = (const float*)d_in[2];
  const float* q1w = (const float*)d_in[3];
  const float* q1b = (const float*)d_in[4];
  const float* k1w = (const float*)d_in[5];
  const float* k1b = (const float*)d_in[6];
  const float* v1w = (const float*)d_in[7];
  const float* v1b = (const float*)d_in[8];
  const float* g1  = (const float*)d_in[9];
  const float* q2w = (const float*)d_in[10];
  const float* q2b = (const float*)d_in[11];
  const float* k2w = (const float*)d_in[12];
  const float* k2b = (const float*)d_in[13];
  const float* v2w = (const float*)d_in[14];
  const float* v2b = (const float*)d_in[15];
  const float* g2  = (const float*)d_in[16];
  char* ws = (char*)d_ws;
  unsigned short* inT = (unsigned short*)(ws);                    // 25,165,824 B (frag-packed)
  unsigned short* Wbf = (unsigned short*)(ws + 25165824);         // 327,680 B (frag-packed)
  unsigned short* Q1  = (unsigned short*)(ws + 25493504);         // 1 MB (row-major)
  unsigned short* K1  = (unsigned short*)(ws + 26542080);         // 1 MB (frag-packed)
  unsigned short* K2  = (unsigned short*)(ws + 27590656);         // 1 MB (frag-packed)
  unsigned short* V1  = (unsigned short*)(ws + 28639232);         // 8 MB (frag-packed)
  unsigned short* V2  = (unsigned short*)(ws + 37027840);         // 8 MB (frag-packed)
  float* outp = (float*)d_out;

  convw_kernel<<<dim3(80), 256, 0, stream>>>(q1w, k1w, k2w, q2w, v1w, v2w, Wbf);
  transpose_kernel<<<dim3(64, 16, 3), 256, 0, stream>>>(x, y, z, inT);
  proj_qk_mfma<<<dim3(64, 4, 3), 256, 0, stream>>>(inT, Wbf, q1b, k1b, k2b, Q1, K1, K2);
  proj_v_mfma<<<dim3(64, 4, 2), 256, 0, stream>>>(inT, Wbf, v1b, v2b, V1, V2);
  fused_attn_kernel<<<dim3(512), 256, 0, stream>>>(Q1, K1, V1, K2, V2, Wbf + 24576, x,
                                                   q2b, g1, g2, outp);
}

// Round 8
// 272.424 us; speedup vs baseline: 2.4977x; 1.0196x over previous
//
#include <hip/hip_runtime.h>
#include <hip/hip_bf16.h>

#define NSEQ 4096
#define CDIM 256
#define CQKD 32
#define LOG2E 1.4426950408889634f

typedef float v4f __attribute__((ext_vector_type(4)));
typedef float v16f __attribute__((ext_vector_type(16)));
typedef short v8s __attribute__((ext_vector_type(8)));

__device__ __forceinline__ float exp2_(float x) { return exp2f(x); }

__device__ __forceinline__ unsigned short f2bf(float x) {
  unsigned u = __builtin_bit_cast(unsigned, x);
  unsigned r = (u + 0x7FFFu + ((u >> 16) & 1u)) >> 16;
  return (unsigned short)r;
}
__device__ __forceinline__ float bf2f(unsigned short s) {
  unsigned u = ((unsigned)s) << 16;
  return __builtin_bit_cast(float, u);
}
__device__ __forceinline__ unsigned int pack_bf16(float a, float b) {
#if __has_builtin(__builtin_amdgcn_cvt_pk_bf16_f32)
  typedef __bf16 v2bf __attribute__((ext_vector_type(2)));
  v2bf r = __builtin_amdgcn_cvt_pk_bf16_f32(a, b);
  return __builtin_bit_cast(unsigned int, r);
#else
  return ((unsigned)f2bf(b) << 16) | (unsigned)f2bf(a);
#endif
}

// LDS-only split barrier: orders LDS producer->consumer WITHOUT draining vmcnt,
// so global prefetch loads stay in flight across the barrier (CK block_sync_lds).
__device__ __forceinline__ void barrier_lds() {
  __asm__ __volatile__("s_waitcnt lgkmcnt(0)\n\ts_barrier" ::: "memory");
}

// ---------------- weight convert+frag-pack (bf16) ----------------
// Wbf (shorts): q1 @0, k1 @8192, k2 @16384 (B-frag 16x16x32, 2 ot x 8 cb)
//               q2 @24576 (A-frag 32x32x16, 16 slabs, pre-scaled log2e)
//               v1 @32768, v2 @98304 (B-frag 16x16x32, 16 ot x 8 cb)
__global__ __launch_bounds__(256) void convw_kernel(
    const float* __restrict__ q1w, const float* __restrict__ k1w,
    const float* __restrict__ k2w, const float* __restrict__ q2w,
    const float* __restrict__ v1w, const float* __restrict__ v2w,
    unsigned short* __restrict__ W) {
  const int s = blockIdx.x * 256 + threadIdx.x;  // v8s slot, 20480 total
  const float* src;
  int o, ch0;
  size_t obase;
  float scale = 1.0f;
  if (s < 3072) {
    const int wsel = s >> 10, r = s & 1023;
    src = wsel == 0 ? q1w : (wsel == 1 ? k1w : k2w);
    const int ot = r >> 9, cb = (r >> 6) & 7, lane = r & 63;
    o = ot * 16 + (lane & 15);
    ch0 = cb * 32 + ((lane >> 4) & 3) * 8;
    obase = (size_t)wsel * 8192 + (size_t)r * 8;
  } else if (s < 19456) {
    const int s2 = s - 3072, which = s2 >> 13, r = s2 & 8191;
    src = which == 0 ? v1w : v2w;
    const int ot = r >> 9, cb = (r >> 6) & 7, lane = r & 63;
    o = ot * 16 + (lane & 15);
    ch0 = cb * 32 + ((lane >> 4) & 3) * 8;
    obase = 32768 + (size_t)which * 65536 + (size_t)r * 8;
  } else {
    const int r = s - 19456;  // 0..1023
    src = q2w;
    const int lane = r & 63;
    o = lane & 31;
    ch0 = (r >> 6) * 16 + (lane >> 5) * 8;
    obase = 24576 + (size_t)r * 8;
    scale = LOG2E;
  }
#pragma unroll
  for (int j = 0; j < 8; ++j)
    W[obase + j] = f2bf(src[o * CDIM + ch0 + j] * scale);
}

// ---------------- transpose+convert: fp32 [b][ch][n] -> bf16 16x16x32-A-frag tiles ----
// inT[src][b][nt256][cb8][lane64][8]: elem j = in[n = nt*16+(lane&15)][ch = cb*32+(lane>>4)*8+j]
__global__ __launch_bounds__(256) void transpose_kernel(
    const float* __restrict__ x, const float* __restrict__ y,
    const float* __restrict__ z, unsigned short* __restrict__ inT) {
  __shared__ unsigned short t[64][76];  // stride 76: rows 8B-aligned for b64 writes
  const int src = blockIdx.z;
  const float* in = src == 0 ? x : (src == 1 ? y : z);
  const int b = blockIdx.y & 3, cht = blockIdx.y >> 2;
  const int n0 = blockIdx.x * 64, ch0 = cht * 64;
  const int tid = threadIdx.x;
  const float* ip = in + ((size_t)(b * CDIM + ch0)) * NSEQ + n0;
  const int rr = tid >> 4;         // 0..15
  const int c4 = (tid & 15) * 4;   // n offset, float4 granularity
#pragma unroll
  for (int p = 0; p < 4; ++p) {
    const int ch = p * 16 + rr;
    float4 v = *(const float4*)(ip + (size_t)ch * NSEQ + c4);
    uint2 pk;
    pk.x = pack_bf16(v.x, v.y);
    pk.y = pack_bf16(v.z, v.w);
    *(uint2*)&t[ch][c4] = pk;
  }
  __syncthreads();
  // emit 8 frags (ntl 0..3 x cbl 0..1); 512 lane-slots, 2 per thread
  unsigned short* op = inT + ((((size_t)src * 4 + b) * 256) + (size_t)blockIdx.x * 4) * 4096 +
                       (size_t)cht * 2 * 512;
#pragma unroll
  for (int sIt = 0; sIt < 2; ++sIt) {
    const int slot = sIt * 256 + tid;
    const int lane = slot & 63, f = slot >> 6;
    const int ntl = f >> 1, cbl = f & 1;
    const int nl = ntl * 16 + (lane & 15);
    const int c0 = cbl * 32 + ((lane >> 4) & 3) * 8;
    union { unsigned short e[8]; v8s v; } u;
#pragma unroll
    for (int j = 0; j < 8; ++j) u.e[j] = t[c0 + j][nl];
    *(v8s*)(op + (size_t)ntl * 4096 + (size_t)cbl * 512 + lane * 8) = u.v;
  }
}

// ---------------- proj Q/K (frag-in, frag-out K; row-major Q) ----------------
__global__ __launch_bounds__(256) void proj_qk_mfma(
    const unsigned short* __restrict__ inT, const unsigned short* __restrict__ Wbf,
    const float* __restrict__ q1b, const float* __restrict__ k1b,
    const float* __restrict__ k2b, unsigned short* __restrict__ Q1,
    unsigned short* __restrict__ K1, unsigned short* __restrict__ K2) {
  __shared__ unsigned short Kt[64][40];
  const int which = blockIdx.z;
  const unsigned short* Wp = Wbf + which * 8192;
  const float* bias = which == 0 ? q1b : (which == 1 ? k1b : k2b);
  const int b = blockIdx.y;
  const int lane = threadIdx.x & 63, w = threadIdx.x >> 6;
  const int quad = lane >> 4, r15 = lane & 15;
  const int nt = blockIdx.x * 4 + w;
  const unsigned short* ip = inT + (((size_t)which * 4 + b) * 256 + nt) * 4096;
  v4f acc[2];
  const v4f vzero = {0.f, 0.f, 0.f, 0.f};
  acc[0] = vzero; acc[1] = vzero;
#pragma unroll
  for (int cb = 0; cb < 8; ++cb) {
    v8s af = *(const v8s*)(ip + cb * 512 + lane * 8);
    v8s b0 = *(const v8s*)(Wp + (0 * 8 + cb) * 512 + lane * 8);
    v8s b1 = *(const v8s*)(Wp + (1 * 8 + cb) * 512 + lane * 8);
    acc[0] = __builtin_amdgcn_mfma_f32_16x16x32_bf16(af, b0, acc[0], 0, 0, 0);
    acc[1] = __builtin_amdgcn_mfma_f32_16x16x32_bf16(af, b1, acc[1], 0, 0, 0);
  }
  const int n0 = nt * 16;
  if (which == 0) {
#pragma unroll
    for (int ot = 0; ot < 2; ++ot) {
      const float bv = bias[ot * 16 + r15];
#pragma unroll
      for (int r = 0; r < 4; ++r)
        Q1[((size_t)b * NSEQ + n0 + quad * 4 + r) * CQKD + ot * 16 + r15] =
            f2bf((acc[ot][r] + bv) * LOG2E);
    }
  } else {
    unsigned short* out = (which == 1 ? K1 : K2) + (size_t)b * (NSEQ / 16) * 512;
#pragma unroll
    for (int ot = 0; ot < 2; ++ot) {
      const float bv = bias[ot * 16 + r15];
#pragma unroll
      for (int r = 0; r < 4; ++r)
        Kt[w * 16 + quad * 4 + r][ot * 16 + r15] = f2bf(acc[ot][r] + bv);
    }
    __syncthreads();
    union { uint2 u2[2]; v8s v; } u;
    u.u2[0] = *(const uint2*)&Kt[w * 16 + r15][quad * 8];
    u.u2[1] = *(const uint2*)&Kt[w * 16 + r15][quad * 8 + 4];
    *(v8s*)(out + ((size_t)nt * 64 + lane) * 8) = u.v;
  }
}

// ---------------- proj V (frag-in, frag-out 32x32x16 A tiles; 8-ot split for TLP) ----
__global__ __launch_bounds__(256) void proj_v_mfma(
    const unsigned short* __restrict__ inT, const unsigned short* __restrict__ Wbf,
    const float* __restrict__ v1b, const float* __restrict__ v2b,
    unsigned short* __restrict__ V1, unsigned short* __restrict__ V2) {
  __shared__ unsigned short Vt[128][72];  // [ch_local][key_local], 18.4 KB
  const int which = blockIdx.z >> 1, oh = blockIdx.z & 1;
  const unsigned short* Wp = Wbf + 32768 + which * 65536 + oh * 8 * 8 * 512;
  const float* bias = (which == 0 ? v1b : v2b) + oh * 128;
  const int b = blockIdx.y;
  unsigned short* out = (which == 0 ? V1 : V2) + (size_t)b * (NSEQ / 16) * 8 * 512;
  const int lane = threadIdx.x & 63, w = threadIdx.x >> 6;
  const int quad = lane >> 4, r15 = lane & 15;
  const int l31 = lane & 31, lh = lane >> 5;
  const int nt = blockIdx.x * 4 + w;
  const unsigned short* ip = inT + (((size_t)(which + 1) * 4 + b) * 256 + nt) * 4096;
  v4f acc[8];
  const v4f vzero = {0.f, 0.f, 0.f, 0.f};
#pragma unroll
  for (int ot = 0; ot < 8; ++ot) acc[ot] = vzero;
#pragma unroll
  for (int cb = 0; cb < 8; ++cb) {
    v8s af = *(const v8s*)(ip + cb * 512 + lane * 8);
#pragma unroll
    for (int ot = 0; ot < 8; ++ot) {
      v8s bf = *(const v8s*)(Wp + ((size_t)(ot * 8 + cb)) * 512 + lane * 8);
      acc[ot] = __builtin_amdgcn_mfma_f32_16x16x32_bf16(af, bf, acc[ot], 0, 0, 0);
    }
  }
#pragma unroll
  for (int ot = 0; ot < 8; ++ot) {
    const int chl = ot * 16 + r15;
    const float bv = bias[chl];
    uint2 pk;
    pk.x = pack_bf16(acc[ot][0] + bv, acc[ot][1] + bv);
    pk.y = pack_bf16(acc[ot][2] + bv, acc[ot][3] + bv);
    *(uint2*)&Vt[chl][w * 16 + quad * 4] = pk;
  }
  __syncthreads();
#pragma unroll
  for (int cbl = 0; cbl < 4; ++cbl) {
    union { uint2 u2[2]; v8s v; } u;
    u.u2[0] = *(const uint2*)&Vt[cbl * 32 + l31][w * 16 + lh * 8];
    u.u2[1] = *(const uint2*)&Vt[cbl * 32 + l31][w * 16 + lh * 8 + 4];
    *(v8s*)(out + (((size_t)nt * 8 + oh * 4 + cbl) * 64 + lane) * 8) = u.v;
  }
}

// ---------------- fused double attention ----------------
// 256 threads = 4 waves: ks = w>>1 (key half), chh = w&1 (channel half). 32 q/block.
// chh-pair shares the S phase through double-buffered LDS P + LDS-only split barrier
// (vmcnt untouched -> V/K prefetch stays in flight). Tiles processed in A/B pairs.
__device__ __forceinline__ void attn_tile(
    const unsigned short* __restrict__ Kl, const unsigned short* __restrict__ Vl,
    unsigned short* pwA, const unsigned short* prBase,
    const v8s qf0, const v8s qf1, int kbA, int dbuf, int tn4,
    const v8s kfu0, const v8s kfu1, v8s& kfn0, v8s& kfn1,
    const v8s* vfu, v8s* vfn, v16f acc[4], float lsum[2]) {
  const v4f vzero4 = {0.f, 0.f, 0.f, 0.f};
  // prefetch next tile's K pair + V frags (consumed next call)
  kfn0 = *(const v8s*)(Kl + (size_t)(tn4 + kbA) * 512);
  kfn1 = *(const v8s*)(Kl + (size_t)(tn4 + kbA + 1) * 512);
#pragma unroll
  for (int t = 0; t < 4; ++t)
#pragma unroll
    for (int s = 0; s < 4; ++s)
      vfn[t * 4 + s] = *(const v8s*)(Vl + ((size_t)(tn4 + s) * 8 + t) * 512);
  // S phase: own kb pair only (chh-shared)
  unsigned short* pw = pwA + dbuf * 2304;
#pragma unroll
  for (int qt = 0; qt < 2; ++qt) {
    const v8s qf = qt ? qf1 : qf0;
#pragma unroll
    for (int kb = 0; kb < 2; ++kb) {
      v4f st = __builtin_amdgcn_mfma_f32_16x16x32_bf16(kb ? kfu1 : kfu0, qf, vzero4, 0, 0, 0);
      float e0 = exp2_(st[0]), e1 = exp2_(st[1]), e2 = exp2_(st[2]), e3 = exp2_(st[3]);
      lsum[qt] += (e0 + e1) + (e2 + e3);
      uint2 pk;
      pk.x = pack_bf16(e0, e1);
      pk.y = pack_bf16(e2, e3);
      *(uint2*)(pw + qt * 16 * 72 + kb * 16) = pk;
    }
  }
  barrier_lds();
  const unsigned short* pr = prBase + dbuf * 2304;
  v8s pf[4];
#pragma unroll
  for (int s = 0; s < 4; ++s) pf[s] = *(const v8s*)(pr + s * 16);
#pragma unroll
  for (int t = 0; t < 4; ++t)
#pragma unroll
    for (int s = 0; s < 4; ++s)
      acc[t] = __builtin_amdgcn_mfma_f32_32x32x16_bf16(vfu[t * 4 + s], pf[s], acc[t], 0, 0, 0);
}

__device__ __forceinline__ void attn_loop(
    const unsigned short* __restrict__ Kp, const unsigned short* __restrict__ Vp,
    unsigned short* Pks, const v8s qf0, const v8s qf1, int ks, int chh, int lane,
    v16f acc[4], float lsum[2]) {
  const int quad = (lane >> 4) & 3, r15 = lane & 15;
  const int l31 = lane & 31, lh = lane >> 5;
  const int kbA = chh * 2;
  const int kt0base = ks * 128;
  const unsigned short* Kl = Kp + (size_t)lane * 8;
  const unsigned short* Vl = Vp + (size_t)lane * 8 + (size_t)chh * 4 * 512;
  unsigned short* pwA = Pks + r15 * 72 + quad * 4 + kbA * 16;
  const unsigned short* prBase = Pks + l31 * 72 + lh * 8;
  v8s kA0, kA1, kB0, kB1;
  v8s vA[16], vB[16];
  kA0 = *(const v8s*)(Kl + (size_t)(kt0base + kbA) * 512);
  kA1 = *(const v8s*)(Kl + (size_t)(kt0base + kbA + 1) * 512);
#pragma unroll
  for (int t = 0; t < 4; ++t)
#pragma unroll
    for (int s = 0; s < 4; ++s)
      vA[t * 4 + s] = *(const v8s*)(Vl + ((size_t)(kt0base + s) * 8 + t) * 512);
  for (int kt = 0; kt < 32; kt += 2) {
    const int tn4a = kt0base + ((kt + 1) & 31) * 4;
    attn_tile(Kl, Vl, pwA, prBase, qf0, qf1, kbA, 0, tn4a, kA0, kA1, kB0, kB1, vA, vB, acc, lsum);
    const int tn4b = kt0base + ((kt + 2) & 31) * 4;
    attn_tile(Kl, Vl, pwA, prBase, qf0, qf1, kbA, 1, tn4b, kB0, kB1, kA0, kA1, vB, vA, acc, lsum);
  }
}

// merge key-halves; afterwards ks==0 waves hold full O, lfq = denom for q=lane&31
__device__ __forceinline__ void merge_ks(
    v16f acc[4], float lsum[2], float* mergeO, float (*lbuf)[32],
    int ks, int chh, int lane, float& lfq) {
  float l0 = lsum[0] + __shfl_xor(lsum[0], 16); l0 += __shfl_xor(l0, 32);
  float l1 = lsum[1] + __shfl_xor(lsum[1], 16); l1 += __shfl_xor(l1, 32);
  if (lane < 16) { lbuf[ks * 2 + chh][lane] = l0; lbuf[ks * 2 + chh][lane + 16] = l1; }
  __syncthreads();  // full barrier: also drains everything before mergeO overwrites P area
  const int l31 = lane & 31, lh = lane >> 5;
  lfq = (lbuf[0][l31] + lbuf[1][l31]) + (lbuf[2][l31] + lbuf[3][l31]);
  if (ks == 1) {
    float* mo = mergeO + chh * (128 * 33);
#pragma unroll
    for (int t = 0; t < 4; ++t)
#pragma unroll
      for (int r = 0; r < 16; ++r) {
        int cl = (r & 3) + 8 * (r >> 2) + 4 * lh;
        mo[(t * 32 + cl) * 33 + l31] = acc[t][r];
      }
  }
  __syncthreads();
  if (ks == 0) {
    const float* mo = mergeO + chh * (128 * 33);
#pragma unroll
    for (int t = 0; t < 4; ++t)
#pragma unroll
      for (int r = 0; r < 16; ++r) {
        int cl = (r & 3) + 8 * (r >> 2) + 4 * lh;
        acc[t][r] += mo[(t * 32 + cl) * 33 + l31];
      }
  }
}

__global__ __launch_bounds__(256, 2) void fused_attn_kernel(
    const unsigned short* __restrict__ Q1g, const unsigned short* __restrict__ K1g,
    const unsigned short* __restrict__ V1g, const unsigned short* __restrict__ K2g,
    const unsigned short* __restrict__ V2g, const unsigned short* __restrict__ W2g,
    const float* __restrict__ x, const float* __restrict__ q2b,
    const float* __restrict__ g1p, const float* __restrict__ g2p,
    float* __restrict__ outp) {
  // P region: [ks][dbuf][32*72] shorts = 18432B, inside 33792B merge area
  __shared__ __align__(16) char uarea[33792];
  __shared__ __align__(16) unsigned short out1T[32 * 264];  // out1 [q][c]
  __shared__ __align__(16) unsigned short q2s[32 * 32];     // q2 [q][o]
  __shared__ float lbuf[4][32];

  const int tid = threadIdx.x;
  const int lane = tid & 63;
  const int w = tid >> 6;
  const int ks = w >> 1;
  const int chh = w & 1;
  const int quad = lane >> 4;
  const int r15 = lane & 15;
  const int l31 = lane & 31, lh = lane >> 5;
  const int b = blockIdx.x & 3;
  const int n0 = (blockIdx.x >> 2) * 32;

  unsigned short* Pks = (unsigned short*)uarea + ks * 2 * 2304;
  float* mergeO = (float*)uarea;

  const float g1 = g1p[0];
  const float g2 = g2p[0];

  const unsigned short* Qp  = Q1g + (size_t)b * NSEQ * CQKD;
  const unsigned short* K1p = K1g + (size_t)b * (NSEQ / 16) * 512;
  const unsigned short* K2p = K2g + (size_t)b * (NSEQ / 16) * 512;
  const unsigned short* V1p = V1g + (size_t)b * (NSEQ / 16) * 8 * 512;
  const unsigned short* V2p = V2g + (size_t)b * (NSEQ / 16) * 8 * 512;

  v8s qf0 = *(const v8s*)(Qp + (n0 + r15) * CQKD + quad * 8);
  v8s qf1 = *(const v8s*)(Qp + (n0 + 16 + r15) * CQKD + quad * 8);

  v16f acc[4];
  float lsum[2] = {0.f, 0.f};
  float lfq;
#pragma unroll
  for (int t = 0; t < 4; ++t) acc[t] = (v16f)(0.f);

  // ---- layer 1 ----
  attn_loop(K1p, V1p, Pks, qf0, qf1, ks, chh, lane, acc, lsum);
  merge_ks(acc, lsum, mergeO, lbuf, ks, chh, lane, lfq);
  if (ks == 0) {
    const float rinv = 1.0f / lfq;
#pragma unroll
    for (int t = 0; t < 4; ++t)
#pragma unroll
      for (int rg = 0; rg < 4; ++rg) {
        const int c = chh * 128 + t * 32 + 8 * rg + 4 * lh;
        float o0 = g1 * (acc[t][rg * 4 + 0] * rinv) + x[((size_t)b * CDIM + c + 0) * NSEQ + n0 + l31];
        float o1 = g1 * (acc[t][rg * 4 + 1] * rinv) + x[((size_t)b * CDIM + c + 1) * NSEQ + n0 + l31];
        float o2 = g1 * (acc[t][rg * 4 + 2] * rinv) + x[((size_t)b * CDIM + c + 2) * NSEQ + n0 + l31];
        float o3 = g1 * (acc[t][rg * 4 + 3] * rinv) + x[((size_t)b * CDIM + c + 3) * NSEQ + n0 + l31];
        uint2 pk;
        pk.x = pack_bf16(o0, o1);
        pk.y = pack_bf16(o2, o3);
        *(uint2*)(out1T + l31 * 264 + c) = pk;
      }
  }
  __syncthreads();

  // ---- q2 projection (wave 0): W2 pre-packed A-frag 32x32x16, pre-scaled ----
  if (w == 0) {
    v16f qacc = (v16f)(0.f);
#pragma unroll
    for (int s = 0; s < 16; ++s) {
      v8s af = *(const v8s*)(W2g + (s * 64 + lane) * 8);
      v8s bf = *(const v8s*)(out1T + l31 * 264 + s * 16 + lh * 8);
      qacc = __builtin_amdgcn_mfma_f32_32x32x16_bf16(af, bf, qacc, 0, 0, 0);
    }
#pragma unroll
    for (int rg = 0; rg < 4; ++rg) {
      const int o = 8 * rg + 4 * lh;
      uint2 pk;
      pk.x = pack_bf16(qacc[rg * 4 + 0] + q2b[o + 0] * LOG2E, qacc[rg * 4 + 1] + q2b[o + 1] * LOG2E);
      pk.y = pack_bf16(qacc[rg * 4 + 2] + q2b[o + 2] * LOG2E, qacc[rg * 4 + 3] + q2b[o + 3] * LOG2E);
      *(uint2*)(q2s + l31 * 32 + o) = pk;
    }
  }
  __syncthreads();

  // ---- layer 2 ----
  qf0 = *(const v8s*)(q2s + r15 * 32 + quad * 8);
  qf1 = *(const v8s*)(q2s + (16 + r15) * 32 + quad * 8);
#pragma unroll
  for (int t = 0; t < 4; ++t) acc[t] = (v16f)(0.f);
  lsum[0] = 0.f; lsum[1] = 0.f;
  attn_loop(K2p, V2p, Pks, qf0, qf1, ks, chh, lane, acc, lsum);
  merge_ks(acc, lsum, mergeO, lbuf, ks, chh, lane, lfq);
  if (ks == 0) {
    const float rinv = 1.0f / lfq;
#pragma unroll
    for (int t = 0; t < 4; ++t)
#pragma unroll
      for (int rg = 0; rg < 4; ++rg) {
        const int c = chh * 128 + t * 32 + 8 * rg + 4 * lh;
#pragma unroll
        for (int i = 0; i < 4; ++i) {
          float res = bf2f(out1T[l31 * 264 + c + i]);
          outp[((size_t)b * CDIM + c + i) * NSEQ + n0 + l31] =
              g2 * (acc[t][rg * 4 + i] * rinv) + res;
        }
      }
  }
}

extern "C" void kernel_launch(void* const* d_in, const int* in_sizes, int n_in,
                              void* d_out, int out_size, void* d_ws, size_t ws_size,
                              hipStream_t stream) {
  const float* x   = (const float*)d_in[0];
  const float* y   = (const float*)d_in[1];
  const float* z   = (const float*)d_in[2];
  const float* q1w = (const float*)d_in[3];
  const float* q1b = (const float*)d_in[4];
  const float* k1w = (const float*)d_in[5];
  const float* k1b = (const float*)d_in[6];
  const float* v1w = (const float*)d_in[7];
  const float* v1b = (const float*)d_in[8];
  const float* g1  = (const float*)d_in[9];
  const float* q2w = (const float*)d_in[10];
  const float* q2b = (const float*)d_in[11];
  const float* k2w = (const float*)d_in[12];
  const float* k2b = (const float*)d_in[13];
  const float* v2w = (const float*)d_in[14];
  const float* v2b = (const float*)d_in[15];
  const float* g2  = (const float*)d_in[16];
  char* ws = (char*)d_ws;
  unsigned short* inT = (unsigned short*)(ws);                    // 25,165,824 B (frag-packed)
  unsigned short* Wbf = (unsigned short*)(ws + 25165824);         // 327,680 B (frag-packed)
  unsigned short* Q1  = (unsigned short*)(ws + 25493504);         // 1 MB (row-major)
  unsigned short* K1  = (unsigned short*)(ws + 26542080);         // 1 MB (frag-packed)
  unsigned short* K2  = (unsigned short*)(ws + 27590656);         // 1 MB (frag-packed)
  unsigned short* V1  = (unsigned short*)(ws + 28639232);         // 8 MB (frag-packed)
  unsigned short* V2  = (unsigned short*)(ws + 37027840);         // 8 MB (frag-packed)
  float* outp = (float*)d_out;

  convw_kernel<<<dim3(80), 256, 0, stream>>>(q1w, k1w, k2w, q2w, v1w, v2w, Wbf);
  transpose_kernel<<<dim3(64, 16, 3), 256, 0, stream>>>(x, y, z, inT);
  proj_qk_mfma<<<dim3(64, 4, 3), 256, 0, stream>>>(inT, Wbf, q1b, k1b, k2b, Q1, K1, K2);
  proj_v_mfma<<<dim3(64, 4, 4), 256, 0, stream>>>(inT, Wbf, v1b, v2b, V1, V2);
  fused_attn_kernel<<<dim3(512), 256, 0, stream>>>(Q1, K1, V1, K2, V2, Wbf + 24576, x,
                                                   q2b, g1, g2, outp);
}

// Round 9
// 237.231 us; speedup vs baseline: 2.8682x; 1.1483x over previous
//
#include <hip/hip_runtime.h>
#include <hip/hip_bf16.h>

#define NSEQ 4096
#define CDIM 256
#define CQKD 32
#define LOG2E 1.4426950408889634f

typedef float v4f __attribute__((ext_vector_type(4)));
typedef float v16f __attribute__((ext_vector_type(16)));
typedef short v8s __attribute__((ext_vector_type(8)));

__device__ __forceinline__ float exp2_(float x) { return exp2f(x); }

__device__ __forceinline__ unsigned short f2bf(float x) {
  unsigned u = __builtin_bit_cast(unsigned, x);
  unsigned r = (u + 0x7FFFu + ((u >> 16) & 1u)) >> 16;
  return (unsigned short)r;
}
__device__ __forceinline__ float bf2f(unsigned short s) {
  unsigned u = ((unsigned)s) << 16;
  return __builtin_bit_cast(float, u);
}
__device__ __forceinline__ unsigned int pack_bf16(float a, float b) {
#if __has_builtin(__builtin_amdgcn_cvt_pk_bf16_f32)
  typedef __bf16 v2bf __attribute__((ext_vector_type(2)));
  v2bf r = __builtin_amdgcn_cvt_pk_bf16_f32(a, b);
  return __builtin_bit_cast(unsigned int, r);
#else
  return ((unsigned)f2bf(b) << 16) | (unsigned)f2bf(a);
#endif
}

// LDS-only split barrier: orders LDS producer->consumer WITHOUT draining vmcnt.
__device__ __forceinline__ void barrier_lds() {
  __asm__ __volatile__("s_waitcnt lgkmcnt(0)\n\ts_barrier" ::: "memory");
}

// ---------------- weight convert+frag-pack (bf16) ----------------
// Wbf (shorts): q1 @0, k1 @8192, k2 @16384 (B-frag 16x16x32, 2 ot x 8 cb)
//               q2 @24576 (A-frag 32x32x16, 16 slabs, pre-scaled log2e)
//               v1 @32768, v2 @98304 (B-frag 16x16x32, 16 ot x 8 cb)
__global__ __launch_bounds__(256) void convw_kernel(
    const float* __restrict__ q1w, const float* __restrict__ k1w,
    const float* __restrict__ k2w, const float* __restrict__ q2w,
    const float* __restrict__ v1w, const float* __restrict__ v2w,
    unsigned short* __restrict__ W) {
  const int s = blockIdx.x * 256 + threadIdx.x;  // v8s slot, 20480 total
  const float* src;
  int o, ch0;
  size_t obase;
  float scale = 1.0f;
  if (s < 3072) {
    const int wsel = s >> 10, r = s & 1023;
    src = wsel == 0 ? q1w : (wsel == 1 ? k1w : k2w);
    const int ot = r >> 9, cb = (r >> 6) & 7, lane = r & 63;
    o = ot * 16 + (lane & 15);
    ch0 = cb * 32 + ((lane >> 4) & 3) * 8;
    obase = (size_t)wsel * 8192 + (size_t)r * 8;
  } else if (s < 19456) {
    const int s2 = s - 3072, which = s2 >> 13, r = s2 & 8191;
    src = which == 0 ? v1w : v2w;
    const int ot = r >> 9, cb = (r >> 6) & 7, lane = r & 63;
    o = ot * 16 + (lane & 15);
    ch0 = cb * 32 + ((lane >> 4) & 3) * 8;
    obase = 32768 + (size_t)which * 65536 + (size_t)r * 8;
  } else {
    const int r = s - 19456;  // 0..1023
    src = q2w;
    const int lane = r & 63;
    o = lane & 31;
    ch0 = (r >> 6) * 16 + (lane >> 5) * 8;
    obase = 24576 + (size_t)r * 8;
    scale = LOG2E;
  }
#pragma unroll
  for (int j = 0; j < 8; ++j)
    W[obase + j] = f2bf(src[o * CDIM + ch0 + j] * scale);
}

// ---------------- prep: one kernel = transpose + Q/K/V projections ----------------
// Per block: (src, b, 64-seq tile). Stage fp32->bf16 LDS [ch][n], build A-frags in
// registers, MFMA against W B-frags, emit Q row-major / K,V frag-packed.
__global__ __launch_bounds__(256) void prep_kernel(
    const float* __restrict__ x, const float* __restrict__ y,
    const float* __restrict__ z, const unsigned short* __restrict__ Wbf,
    const float* __restrict__ q1b, const float* __restrict__ k1b,
    const float* __restrict__ k2b, const float* __restrict__ v1b,
    const float* __restrict__ v2b, unsigned short* __restrict__ Q1,
    unsigned short* __restrict__ K1, unsigned short* __restrict__ K2,
    unsigned short* __restrict__ V1, unsigned short* __restrict__ V2) {
  __shared__ unsigned short t[256][72];  // staging [ch][n]; reused as Vt [ch][key]
  __shared__ unsigned short Kt[64][40];
  const int src = blockIdx.z;
  const float* in = src == 0 ? x : (src == 1 ? y : z);
  const int b = blockIdx.y;
  const int n0 = blockIdx.x * 64;
  const int tid = threadIdx.x, lane = tid & 63, w = tid >> 6;
  const int quad = lane >> 4, r15 = lane & 15, l31 = lane & 31, lh = lane >> 5;
  // phase 1: stage
  const float* ip = in + (size_t)(b * CDIM) * NSEQ + n0;
  {
    const int chb = tid >> 4, c4 = (tid & 15) * 4;
#pragma unroll
    for (int p = 0; p < 16; ++p) {
      const int ch = p * 16 + chb;
      float4 v = *(const float4*)(ip + (size_t)ch * NSEQ + c4);
      uint2 pk;
      pk.x = pack_bf16(v.x, v.y);
      pk.y = pack_bf16(v.z, v.w);
      *(uint2*)&t[ch][c4] = pk;
    }
  }
  __syncthreads();
  // phase 2: A-frags for this wave's 16-seq tile (nt local = w)
  v8s af[8];
#pragma unroll
  for (int cb = 0; cb < 8; ++cb) {
    union { unsigned short e[8]; v8s v; } u;
#pragma unroll
    for (int j = 0; j < 8; ++j) u.e[j] = t[cb * 32 + quad * 8 + j][w * 16 + r15];
    af[cb] = u.v;
  }
  const int nt = blockIdx.x * 4 + w;
  // Q/K projection
  const unsigned short* Wqk = Wbf + src * 8192;
  v4f a0 = {0.f, 0.f, 0.f, 0.f}, a1 = a0;
#pragma unroll
  for (int cb = 0; cb < 8; ++cb) {
    v8s b0 = *(const v8s*)(Wqk + (size_t)cb * 512 + lane * 8);
    v8s b1 = *(const v8s*)(Wqk + (size_t)(8 + cb) * 512 + lane * 8);
    a0 = __builtin_amdgcn_mfma_f32_16x16x32_bf16(af[cb], b0, a0, 0, 0, 0);
    a1 = __builtin_amdgcn_mfma_f32_16x16x32_bf16(af[cb], b1, a1, 0, 0, 0);
  }
  if (src == 0) {
#pragma unroll
    for (int r = 0; r < 4; ++r) {
      Q1[((size_t)b * NSEQ + nt * 16 + quad * 4 + r) * CQKD + r15] =
          f2bf((a0[r] + q1b[r15]) * LOG2E);
      Q1[((size_t)b * NSEQ + nt * 16 + quad * 4 + r) * CQKD + 16 + r15] =
          f2bf((a1[r] + q1b[16 + r15]) * LOG2E);
    }
    return;
  }
  const float* kbias = src == 1 ? k1b : k2b;
#pragma unroll
  for (int r = 0; r < 4; ++r) {
    Kt[w * 16 + quad * 4 + r][r15] = f2bf(a0[r] + kbias[r15]);
    Kt[w * 16 + quad * 4 + r][16 + r15] = f2bf(a1[r] + kbias[16 + r15]);
  }
  // V projection (16 ot of 16 ch)
  const unsigned short* Wv = Wbf + 32768 + (src - 1) * 65536;
  const float* vbias = src == 1 ? v1b : v2b;
  v4f vacc[16];
#pragma unroll
  for (int ot = 0; ot < 16; ++ot) vacc[ot] = (v4f){0.f, 0.f, 0.f, 0.f};
#pragma unroll
  for (int cb = 0; cb < 8; ++cb) {
    const v8s afc = af[cb];
#pragma unroll
    for (int ot = 0; ot < 16; ++ot) {
      v8s bf = *(const v8s*)(Wv + (size_t)(ot * 8 + cb) * 512 + lane * 8);
      vacc[ot] = __builtin_amdgcn_mfma_f32_16x16x32_bf16(afc, bf, vacc[ot], 0, 0, 0);
    }
  }
  __syncthreads();  // af reads done + Kt written -> safe to reuse t as Vt
  // Vt write [ch][key_local]
#pragma unroll
  for (int ot = 0; ot < 16; ++ot) {
    const int ch = ot * 16 + r15;
    const float bv = vbias[ch];
    uint2 pk;
    pk.x = pack_bf16(vacc[ot][0] + bv, vacc[ot][1] + bv);
    pk.y = pack_bf16(vacc[ot][2] + bv, vacc[ot][3] + bv);
    *(uint2*)&t[ch][w * 16 + quad * 4] = pk;
  }
  // K frag out (16x16x32 A-frag order)
  {
    unsigned short* Kout = (src == 1 ? K1 : K2) + (size_t)b * (NSEQ / 16) * 512;
    *(v8s*)(Kout + ((size_t)nt * 64 + lane) * 8) = *(const v8s*)&Kt[w * 16 + r15][quad * 8];
  }
  __syncthreads();  // Vt complete
  // V frag out (32x32x16 A-frag order)
  unsigned short* Vout = (src == 1 ? V1 : V2) + (size_t)b * (NSEQ / 16) * 8 * 512;
#pragma unroll
  for (int chb = 0; chb < 8; ++chb)
    *(v8s*)(Vout + (((size_t)nt * 8 + chb) * 64 + lane) * 8) =
        *(const v8s*)&t[chb * 32 + l31][w * 16 + lh * 8];
}

// ---------------- fused double attention ----------------
// 512 threads = 8 waves, 64 queries/block, grid 256 (1 block/CU). No key-split.
// Wave w: S for key-block kb16 = tile*8+w (4 qt MFMAs), PV for channel slab chb=w.
// P[64q][128k] shared via double-buffered LDS + lds-only barrier; V/K prefetch 1 tile.
#define PSTR 136  // shorts; rows 16B-aligned

__device__ __forceinline__ void attn_tile(
    const unsigned short* __restrict__ Kl, const unsigned short* __restrict__ Vl,
    unsigned short* __restrict__ P, const v8s qf[4], int w, int lane,
    int pbuf, int tn, const v8s kfu, const v8s* vfu, v8s& kfn, v8s* vfn,
    v16f acc[2], float lsum[4]) {
  const v4f vzero4 = {0.f, 0.f, 0.f, 0.f};
  const int quad = (lane >> 4) & 3, r15 = lane & 15;
  const int l31 = lane & 31, lh = lane >> 5;
  // prefetch next tile
  kfn = *(const v8s*)(Kl + (size_t)tn * 4096);
#pragma unroll
  for (int s = 0; s < 8; ++s)
    vfn[s] = *(const v8s*)(Vl + ((size_t)tn * 64 + s * 8) * 512);
  // S phase: this wave's 16-key block, all 4 q-tiles
  unsigned short* pw = P + pbuf * (64 * PSTR) + w * 16 + quad * 4;
#pragma unroll
  for (int qt = 0; qt < 4; ++qt) {
    v4f st = __builtin_amdgcn_mfma_f32_16x16x32_bf16(kfu, qf[qt], vzero4, 0, 0, 0);
    float e0 = exp2_(st[0]), e1 = exp2_(st[1]), e2 = exp2_(st[2]), e3 = exp2_(st[3]);
    lsum[qt] += (e0 + e1) + (e2 + e3);
    uint2 pk;
    pk.x = pack_bf16(e0, e1);
    pk.y = pack_bf16(e2, e3);
    *(uint2*)(pw + (qt * 16 + r15) * PSTR) = pk;
  }
  barrier_lds();
  // PV phase: this wave's 32-ch slab over all 128 keys, both 32-q halves
  const unsigned short* pb = P + pbuf * (64 * PSTR);
#pragma unroll
  for (int s = 0; s < 8; ++s) {
    v8s pf0 = *(const v8s*)(pb + (size_t)l31 * PSTR + s * 16 + lh * 8);
    v8s pf1 = *(const v8s*)(pb + (size_t)(32 + l31) * PSTR + s * 16 + lh * 8);
    acc[0] = __builtin_amdgcn_mfma_f32_32x32x16_bf16(vfu[s], pf0, acc[0], 0, 0, 0);
    acc[1] = __builtin_amdgcn_mfma_f32_32x32x16_bf16(vfu[s], pf1, acc[1], 0, 0, 0);
  }
}

__device__ __forceinline__ void attn_loop(
    const unsigned short* __restrict__ Kp, const unsigned short* __restrict__ Vp,
    unsigned short* __restrict__ P, const v8s qf[4], int w, int lane,
    v16f acc[2], float lsum[4]) {
  const unsigned short* Kl = Kp + (size_t)w * 512 + lane * 8;
  const unsigned short* Vl = Vp + (size_t)w * 512 + lane * 8;
  v8s kA, kB, vA[8], vB[8];
  kA = *(const v8s*)(Kl);
#pragma unroll
  for (int s = 0; s < 8; ++s) vA[s] = *(const v8s*)(Vl + (size_t)s * 8 * 512);
  for (int kt = 0; kt < 32; kt += 2) {
    attn_tile(Kl, Vl, P, qf, w, lane, 0, (kt + 1) & 31, kA, vA, kB, vB, acc, lsum);
    attn_tile(Kl, Vl, P, qf, w, lane, 1, (kt + 2) & 31, kB, vB, kA, vA, acc, lsum);
  }
}

__global__ __launch_bounds__(512, 2) void fused_attn_kernel(
    const unsigned short* __restrict__ Q1g, const unsigned short* __restrict__ K1g,
    const unsigned short* __restrict__ V1g, const unsigned short* __restrict__ K2g,
    const unsigned short* __restrict__ V2g, const unsigned short* __restrict__ W2g,
    const float* __restrict__ x, const float* __restrict__ q2b,
    const float* __restrict__ g1p, const float* __restrict__ g2p,
    float* __restrict__ outp) {
  __shared__ __align__(16) unsigned short P[2 * 64 * PSTR];   // 34.8 KB
  __shared__ __align__(16) unsigned short out1T[64 * 264];    // 33.8 KB [q][c]
  __shared__ __align__(16) unsigned short q2s[64 * 32];       // 4 KB [q][o]
  __shared__ float lbuf[8][64];

  const int tid = threadIdx.x;
  const int lane = tid & 63;
  const int w = tid >> 6;  // 0..7
  const int quad = lane >> 4;
  const int r15 = lane & 15;
  const int l31 = lane & 31, lh = lane >> 5;
  const int b = blockIdx.x & 3;
  const int n0 = (blockIdx.x >> 2) * 64;

  const float g1 = g1p[0];
  const float g2 = g2p[0];

  const unsigned short* Qp  = Q1g + (size_t)b * NSEQ * CQKD;
  const unsigned short* K1p = K1g + (size_t)b * (NSEQ / 16) * 512;
  const unsigned short* K2p = K2g + (size_t)b * (NSEQ / 16) * 512;
  const unsigned short* V1p = V1g + (size_t)b * (NSEQ / 16) * 8 * 512;
  const unsigned short* V2p = V2g + (size_t)b * (NSEQ / 16) * 8 * 512;

  v8s qf[4];
#pragma unroll
  for (int qt = 0; qt < 4; ++qt)
    qf[qt] = *(const v8s*)(Qp + (n0 + qt * 16 + r15) * CQKD + quad * 8);

  v16f acc[2];
  float lsum[4] = {0.f, 0.f, 0.f, 0.f};
  acc[0] = (v16f)(0.f); acc[1] = (v16f)(0.f);

  // ---- layer 1 ----
  attn_loop(K1p, V1p, P, qf, w, lane, acc, lsum);
#pragma unroll
  for (int qt = 0; qt < 4; ++qt) {
    lsum[qt] += __shfl_xor(lsum[qt], 16);
    lsum[qt] += __shfl_xor(lsum[qt], 32);
  }
  if (lane < 16) {
#pragma unroll
    for (int qt = 0; qt < 4; ++qt) lbuf[w][qt * 16 + lane] = lsum[qt];
  }
  __syncthreads();
  float rinv[2];
#pragma unroll
  for (int qh = 0; qh < 2; ++qh) {
    const int q = qh * 32 + l31;
    float d = 0.f;
#pragma unroll
    for (int ww = 0; ww < 8; ++ww) d += lbuf[ww][q];
    rinv[qh] = 1.0f / d;
  }
#pragma unroll
  for (int qh = 0; qh < 2; ++qh) {
    const int q = qh * 32 + l31;
#pragma unroll
    for (int rg = 0; rg < 4; ++rg) {
      const int c = w * 32 + 8 * rg + 4 * lh;
      float o0 = g1 * (acc[qh][rg * 4 + 0] * rinv[qh]) + x[((size_t)b * CDIM + c + 0) * NSEQ + n0 + q];
      float o1 = g1 * (acc[qh][rg * 4 + 1] * rinv[qh]) + x[((size_t)b * CDIM + c + 1) * NSEQ + n0 + q];
      float o2 = g1 * (acc[qh][rg * 4 + 2] * rinv[qh]) + x[((size_t)b * CDIM + c + 2) * NSEQ + n0 + q];
      float o3 = g1 * (acc[qh][rg * 4 + 3] * rinv[qh]) + x[((size_t)b * CDIM + c + 3) * NSEQ + n0 + q];
      uint2 pk;
      pk.x = pack_bf16(o0, o1);
      pk.y = pack_bf16(o2, o3);
      *(uint2*)(out1T + (size_t)q * 264 + c) = pk;
    }
  }
  __syncthreads();

  // ---- q2 projection (waves 0,1 handle q-halves): W2 A-frag 32x32x16 pre-scaled ----
  if (w < 2) {
    const int qh = w;
    v16f qacc = (v16f)(0.f);
#pragma unroll
    for (int s = 0; s < 16; ++s) {
      v8s af = *(const v8s*)(W2g + (size_t)(s * 64 + lane) * 8);
      v8s bf = *(const v8s*)(out1T + (size_t)(qh * 32 + l31) * 264 + s * 16 + lh * 8);
      qacc = __builtin_amdgcn_mfma_f32_32x32x16_bf16(af, bf, qacc, 0, 0, 0);
    }
#pragma unroll
    for (int rg = 0; rg < 4; ++rg) {
      const int o = 8 * rg + 4 * lh;
      uint2 pk;
      pk.x = pack_bf16(qacc[rg * 4 + 0] + q2b[o + 0] * LOG2E, qacc[rg * 4 + 1] + q2b[o + 1] * LOG2E);
      pk.y = pack_bf16(qacc[rg * 4 + 2] + q2b[o + 2] * LOG2E, qacc[rg * 4 + 3] + q2b[o + 3] * LOG2E);
      *(uint2*)(q2s + (size_t)(qh * 32 + l31) * 32 + o) = pk;
    }
  }
  __syncthreads();

  // ---- layer 2 ----
#pragma unroll
  for (int qt = 0; qt < 4; ++qt)
    qf[qt] = *(const v8s*)(q2s + (qt * 16 + r15) * 32 + quad * 8);
  acc[0] = (v16f)(0.f); acc[1] = (v16f)(0.f);
#pragma unroll
  for (int qt = 0; qt < 4; ++qt) lsum[qt] = 0.f;
  attn_loop(K2p, V2p, P, qf, w, lane, acc, lsum);
#pragma unroll
  for (int qt = 0; qt < 4; ++qt) {
    lsum[qt] += __shfl_xor(lsum[qt], 16);
    lsum[qt] += __shfl_xor(lsum[qt], 32);
  }
  __syncthreads();  // lbuf layer-1 values fully consumed
  if (lane < 16) {
#pragma unroll
    for (int qt = 0; qt < 4; ++qt) lbuf[w][qt * 16 + lane] = lsum[qt];
  }
  __syncthreads();
#pragma unroll
  for (int qh = 0; qh < 2; ++qh) {
    const int q = qh * 32 + l31;
    float d = 0.f;
#pragma unroll
    for (int ww = 0; ww < 8; ++ww) d += lbuf[ww][q];
    rinv[qh] = 1.0f / d;
  }
#pragma unroll
  for (int qh = 0; qh < 2; ++qh) {
    const int q = qh * 32 + l31;
#pragma unroll
    for (int rg = 0; rg < 4; ++rg) {
      const int c = w * 32 + 8 * rg + 4 * lh;
#pragma unroll
      for (int i = 0; i < 4; ++i) {
        float res = bf2f(out1T[(size_t)q * 264 + c + i]);
        outp[((size_t)b * CDIM + c + i) * NSEQ + n0 + q] =
            g2 * (acc[qh][rg * 4 + i] * rinv[qh]) + res;
      }
    }
  }
}

extern "C" void kernel_launch(void* const* d_in, const int* in_sizes, int n_in,
                              void* d_out, int out_size, void* d_ws, size_t ws_size,
                              hipStream_t stream) {
  const float* x   = (const float*)d_in[0];
  const float* y   = (const float*)d_in[1];
  const float* z   = (const float*)d_in[2];
  const float* q1w = (const float*)d_in[3];
  const float* q1b = (const float*)d_in[4];
  const float* k1w = (const float*)d_in[5];
  const float* k1b = (const float*)d_in[6];
  const float* v1w = (const float*)d_in[7];
  const float* v1b = (const float*)d_in[8];
  const float* g1  = (const float*)d_in[9];
  const float* q2w = (const float*)d_in[10];
  const float* q2b = (const float*)d_in[11];
  const float* k2w = (const float*)d_in[12];
  const float* k2b = (const float*)d_in[13];
  const float* v2w = (const float*)d_in[14];
  const float* v2b = (const float*)d_in[15];
  const float* g2  = (const float*)d_in[16];
  char* ws = (char*)d_ws;
  unsigned short* Wbf = (unsigned short*)(ws);                 // 327,680 B
  unsigned short* Q1  = (unsigned short*)(ws + 327680);        // 1 MB
  unsigned short* K1  = (unsigned short*)(ws + 1376256);       // 1 MB
  unsigned short* K2  = (unsigned short*)(ws + 2424832);       // 1 MB
  unsigned short* V1  = (unsigned short*)(ws + 3473408);       // 8 MB
  unsigned short* V2  = (unsigned short*)(ws + 11862016);      // 8 MB -> 20,250,624 total
  float* outp = (float*)d_out;

  convw_kernel<<<dim3(80), 256, 0, stream>>>(q1w, k1w, k2w, q2w, v1w, v2w, Wbf);
  prep_kernel<<<dim3(64, 4, 3), 256, 0, stream>>>(x, y, z, Wbf, q1b, k1b, k2b, v1b,
                                                  v2b, Q1, K1, K2, V1, V2);
  fused_attn_kernel<<<dim3(256), 512, 0, stream>>>(Q1, K1, V1, K2, V2, Wbf + 24576, x,
                                                   q2b, g1, g2, outp);
}

// Round 10
// 222.097 us; speedup vs baseline: 3.0636x; 1.0681x over previous
//
#include <hip/hip_runtime.h>
#include <hip/hip_bf16.h>

#define NSEQ 4096
#define CDIM 256
#define CQKD 32
#define LOG2E 1.4426950408889634f

typedef float v4f __attribute__((ext_vector_type(4)));
typedef float v16f __attribute__((ext_vector_type(16)));
typedef short v8s __attribute__((ext_vector_type(8)));
typedef unsigned long long u64;

__device__ __forceinline__ float exp2_(float x) {
#if __has_builtin(__builtin_amdgcn_exp2f)
  return __builtin_amdgcn_exp2f(x);
#else
  float r;
  __asm__("v_exp_f32 %0, %1" : "=v"(r) : "v"(x));
  return r;
#endif
}

__device__ __forceinline__ unsigned short f2bf(float x) {
  unsigned u = __builtin_bit_cast(unsigned, x);
  unsigned r = (u + 0x7FFFu + ((u >> 16) & 1u)) >> 16;
  return (unsigned short)r;
}
__device__ __forceinline__ float bf2f(unsigned short s) {
  unsigned u = ((unsigned)s) << 16;
  return __builtin_bit_cast(float, u);
}
__device__ __forceinline__ unsigned int pack_bf16(float a, float b) {
#if __has_builtin(__builtin_amdgcn_cvt_pk_bf16_f32)
  typedef __bf16 v2bf __attribute__((ext_vector_type(2)));
  v2bf r = __builtin_amdgcn_cvt_pk_bf16_f32(a, b);
  return __builtin_bit_cast(unsigned int, r);
#else
  return ((unsigned)f2bf(b) << 16) | (unsigned)f2bf(a);
#endif
}

// fp8 e4m3fn (OCP) encode, software fallback
__device__ __forceinline__ unsigned char f2e4m3(float x) {
  unsigned u = __builtin_bit_cast(unsigned, x);
  unsigned s = (u >> 24) & 0x80u;
  unsigned au = u & 0x7fffffffu;
  if (au > 0x43e00000u) return (unsigned char)(s | 0x7eu);  // clamp to 448
  if (au < 0x3c800000u) {                                   // subnormal range (<2^-6)
    float ax = __builtin_bit_cast(float, au);
    int q = (int)(ax * 512.0f + 0.5f);
    if (q > 7) q = 7;
    return (unsigned char)(s | (unsigned)q);
  }
  int e = (int)((au >> 23) & 0xffu) - 127 + 7;
  unsigned m = au & 0x7fffffu;
  unsigned mr = m + 0x7ffffu + ((m >> 20) & 1u);
  if (mr >= 0x800000u) { mr -= 0x800000u; e += 1; if (e >= 16) return (unsigned char)(s | 0x7e); }
  return (unsigned char)(s | ((unsigned)e << 3) | (mr >> 20));
}
__device__ __forceinline__ unsigned int pack4_fp8(float a, float b, float c, float d) {
#if __has_builtin(__builtin_amdgcn_cvt_pk_fp8_f32)
  int v = 0;
  v = __builtin_amdgcn_cvt_pk_fp8_f32(a, b, v, false);
  v = __builtin_amdgcn_cvt_pk_fp8_f32(c, d, v, true);
  return (unsigned int)v;
#else
  return (unsigned)f2e4m3(a) | ((unsigned)f2e4m3(b) << 8) |
         ((unsigned)f2e4m3(c) << 16) | ((unsigned)f2e4m3(d) << 24);
#endif
}

// LDS-only split barrier (orders LDS producer->consumer without draining vmcnt)
__device__ __forceinline__ void barrier_lds() {
  __asm__ __volatile__("s_waitcnt lgkmcnt(0)\n\ts_barrier" ::: "memory");
}

// ---------------- weight convert+frag-pack (bf16) ----------------
__global__ __launch_bounds__(256) void convw_kernel(
    const float* __restrict__ q1w, const float* __restrict__ k1w,
    const float* __restrict__ k2w, const float* __restrict__ q2w,
    const float* __restrict__ v1w, const float* __restrict__ v2w,
    unsigned short* __restrict__ W) {
  const int s = blockIdx.x * 256 + threadIdx.x;  // v8s slot, 20480 total
  const float* src;
  int o, ch0;
  size_t obase;
  float scale = 1.0f;
  if (s < 3072) {
    const int wsel = s >> 10, r = s & 1023;
    src = wsel == 0 ? q1w : (wsel == 1 ? k1w : k2w);
    const int ot = r >> 9, cb = (r >> 6) & 7, lane = r & 63;
    o = ot * 16 + (lane & 15);
    ch0 = cb * 32 + ((lane >> 4) & 3) * 8;
    obase = (size_t)wsel * 8192 + (size_t)r * 8;
  } else if (s < 19456) {
    const int s2 = s - 3072, which = s2 >> 13, r = s2 & 8191;
    src = which == 0 ? v1w : v2w;
    const int ot = r >> 9, cb = (r >> 6) & 7, lane = r & 63;
    o = ot * 16 + (lane & 15);
    ch0 = cb * 32 + ((lane >> 4) & 3) * 8;
    obase = 32768 + (size_t)which * 65536 + (size_t)r * 8;
  } else {
    const int r = s - 19456;
    src = q2w;
    const int lane = r & 63;
    o = lane & 31;
    ch0 = (r >> 6) * 16 + (lane >> 5) * 8;
    obase = 24576 + (size_t)r * 8;
    scale = LOG2E;
  }
#pragma unroll
  for (int j = 0; j < 8; ++j)
    W[obase + j] = f2bf(src[o * CDIM + ch0 + j] * scale);
}

// ---------------- prep: transpose + Q/K/V projections (V emitted fp8) ----------------
__global__ __launch_bounds__(256) void prep_kernel(
    const float* __restrict__ x, const float* __restrict__ y,
    const float* __restrict__ z, const unsigned short* __restrict__ Wbf,
    const float* __restrict__ q1b, const float* __restrict__ k1b,
    const float* __restrict__ k2b, const float* __restrict__ v1b,
    const float* __restrict__ v2b, unsigned short* __restrict__ Q1,
    unsigned short* __restrict__ K1, unsigned short* __restrict__ K2,
    unsigned char* __restrict__ V1, unsigned char* __restrict__ V2) {
  __shared__ unsigned short t[256][72];  // staging [ch][n] bf16; reused as fp8 Vt
  __shared__ unsigned short Kt[64][40];
  const int src = blockIdx.z;
  const float* in = src == 0 ? x : (src == 1 ? y : z);
  const int b = blockIdx.y;
  const int n0 = blockIdx.x * 64;
  const int tid = threadIdx.x, lane = tid & 63, w = tid >> 6;
  const int quad = lane >> 4, r15 = lane & 15, l31 = lane & 31, lh = lane >> 5;
  const float* ip = in + (size_t)(b * CDIM) * NSEQ + n0;
  {
    const int chb = tid >> 4, c4 = (tid & 15) * 4;
#pragma unroll
    for (int p = 0; p < 16; ++p) {
      const int ch = p * 16 + chb;
      float4 v = *(const float4*)(ip + (size_t)ch * NSEQ + c4);
      uint2 pk;
      pk.x = pack_bf16(v.x, v.y);
      pk.y = pack_bf16(v.z, v.w);
      *(uint2*)&t[ch][c4] = pk;
    }
  }
  __syncthreads();
  v8s af[8];
#pragma unroll
  for (int cb = 0; cb < 8; ++cb) {
    union { unsigned short e[8]; v8s v; } u;
#pragma unroll
    for (int j = 0; j < 8; ++j) u.e[j] = t[cb * 32 + quad * 8 + j][w * 16 + r15];
    af[cb] = u.v;
  }
  const int nt = blockIdx.x * 4 + w;
  const unsigned short* Wqk = Wbf + src * 8192;
  v4f a0 = {0.f, 0.f, 0.f, 0.f}, a1 = a0;
#pragma unroll
  for (int cb = 0; cb < 8; ++cb) {
    v8s b0 = *(const v8s*)(Wqk + (size_t)cb * 512 + lane * 8);
    v8s b1 = *(const v8s*)(Wqk + (size_t)(8 + cb) * 512 + lane * 8);
    a0 = __builtin_amdgcn_mfma_f32_16x16x32_bf16(af[cb], b0, a0, 0, 0, 0);
    a1 = __builtin_amdgcn_mfma_f32_16x16x32_bf16(af[cb], b1, a1, 0, 0, 0);
  }
  if (src == 0) {
#pragma unroll
    for (int r = 0; r < 4; ++r) {
      Q1[((size_t)b * NSEQ + nt * 16 + quad * 4 + r) * CQKD + r15] =
          f2bf((a0[r] + q1b[r15]) * LOG2E);
      Q1[((size_t)b * NSEQ + nt * 16 + quad * 4 + r) * CQKD + 16 + r15] =
          f2bf((a1[r] + q1b[16 + r15]) * LOG2E);
    }
    return;
  }
  const float* kbias = src == 1 ? k1b : k2b;
#pragma unroll
  for (int r = 0; r < 4; ++r) {
    Kt[w * 16 + quad * 4 + r][r15] = f2bf(a0[r] + kbias[r15]);
    Kt[w * 16 + quad * 4 + r][16 + r15] = f2bf(a1[r] + kbias[16 + r15]);
  }
  const unsigned short* Wv = Wbf + 32768 + (src - 1) * 65536;
  const float* vbias = src == 1 ? v1b : v2b;
  v4f vacc[16];
#pragma unroll
  for (int ot = 0; ot < 16; ++ot) vacc[ot] = (v4f){0.f, 0.f, 0.f, 0.f};
#pragma unroll
  for (int cb = 0; cb < 8; ++cb) {
    const v8s afc = af[cb];
#pragma unroll
    for (int ot = 0; ot < 16; ++ot) {
      v8s bf = *(const v8s*)(Wv + (size_t)(ot * 8 + cb) * 512 + lane * 8);
      vacc[ot] = __builtin_amdgcn_mfma_f32_16x16x32_bf16(afc, bf, vacc[ot], 0, 0, 0);
    }
  }
  __syncthreads();  // staging reads done -> reuse t as fp8 Vt (rows 72 B)
  unsigned char* Vt8 = (unsigned char*)t;
#pragma unroll
  for (int ot = 0; ot < 16; ++ot) {
    const int ch = ot * 16 + r15;
    const float bv = vbias[ch];
    *(unsigned int*)&Vt8[(size_t)ch * 72 + w * 16 + quad * 4] =
        pack4_fp8(vacc[ot][0] + bv, vacc[ot][1] + bv, vacc[ot][2] + bv, vacc[ot][3] + bv);
  }
  {
    unsigned short* Kout = (src == 1 ? K1 : K2) + (size_t)b * (NSEQ / 16) * 512;
    *(v8s*)(Kout + ((size_t)nt * 64 + lane) * 8) = *(const v8s*)&Kt[w * 16 + r15][quad * 8];
  }
  __syncthreads();  // Vt complete
  unsigned char* Vout = (src == 1 ? V1 : V2) + (size_t)b * (NSEQ / 16) * 8 * 512;
#pragma unroll
  for (int chb = 0; chb < 8; ++chb)
    *(u64*)(Vout + (((size_t)nt * 8 + chb) * 64 + lane) * 8) =
        *(const u64*)&Vt8[(size_t)(chb * 32 + l31) * 72 + w * 16 + lh * 8];
}

// ---------------- fused double attention (fp8 PV) ----------------
// 512 thr = 8 waves, 64 q/block, grid 256. Wave w: S key-block kb16=tile*8+w (bf16),
// PV ch-slab chb=w (fp8 32x32x16). Per-q global max from a cheap standalone pass
// makes exp2(s-m) in (0,1] -> e4m3-safe. P fp8 in LDS (b32 write / b64 read).

__device__ __forceinline__ void max_pass(
    const unsigned short* __restrict__ Kp, const v8s qf[4], int w, int lane,
    float (*lbuf)[64], float m[4]) {
  const v4f vzero4 = {0.f, 0.f, 0.f, 0.f};
  const int r15 = lane & 15;
  const unsigned short* Kl = Kp + (size_t)w * 512 + lane * 8;
  v8s kA = *(const v8s*)(Kl);
#pragma unroll
  for (int qt = 0; qt < 4; ++qt) m[qt] = -3.0e38f;
  for (int kt = 0; kt < 32; ++kt) {
    v8s kB = *(const v8s*)(Kl + (size_t)((kt + 1) & 31) * 4096);
#pragma unroll
    for (int qt = 0; qt < 4; ++qt) {
      v4f st = __builtin_amdgcn_mfma_f32_16x16x32_bf16(kA, qf[qt], vzero4, 0, 0, 0);
      m[qt] = fmaxf(m[qt], fmaxf(fmaxf(st[0], st[1]), fmaxf(st[2], st[3])));
    }
    kA = kB;
  }
#pragma unroll
  for (int qt = 0; qt < 4; ++qt) {
    m[qt] = fmaxf(m[qt], __shfl_xor(m[qt], 16));
    m[qt] = fmaxf(m[qt], __shfl_xor(m[qt], 32));
  }
  if (lane < 16) {
#pragma unroll
    for (int qt = 0; qt < 4; ++qt) lbuf[w][qt * 16 + lane] = m[qt];
  }
  __syncthreads();
#pragma unroll
  for (int qt = 0; qt < 4; ++qt) {
    float mm = lbuf[0][qt * 16 + r15];
#pragma unroll
    for (int ww = 1; ww < 8; ++ww) mm = fmaxf(mm, lbuf[ww][qt * 16 + r15]);
    m[qt] = mm;
  }
  __syncthreads();
}

__device__ __forceinline__ void attn_tile(
    const unsigned short* __restrict__ Kl, const unsigned char* __restrict__ Vl,
    unsigned char* __restrict__ P, const v8s qf[4], const float m[4], int w, int lane,
    int pbuf, int tn, const v8s kfu, const u64* vfu, v8s& kfn, u64* vfn,
    v16f acc[2], float lsum[4]) {
  const v4f vzero4 = {0.f, 0.f, 0.f, 0.f};
  const int quad = (lane >> 4) & 3, r15 = lane & 15;
  const int l31 = lane & 31, lh = lane >> 5;
  // prefetch next tile
  kfn = *(const v8s*)(Kl + (size_t)tn * 4096);
#pragma unroll
  for (int s = 0; s < 8; ++s)
    vfn[s] = *(const u64*)(Vl + (size_t)tn * 32768 + s * 4096);
  // S phase (bf16) -> exp2(s - m) -> fp8 P
  unsigned char* pw = P + pbuf * 8704 + w * 16 + quad * 4;
#pragma unroll
  for (int qt = 0; qt < 4; ++qt) {
    v4f st = __builtin_amdgcn_mfma_f32_16x16x32_bf16(kfu, qf[qt], vzero4, 0, 0, 0);
    float e0 = exp2_(st[0] - m[qt]), e1 = exp2_(st[1] - m[qt]);
    float e2 = exp2_(st[2] - m[qt]), e3 = exp2_(st[3] - m[qt]);
    lsum[qt] += (e0 + e1) + (e2 + e3);
    *(unsigned int*)(pw + (size_t)(qt * 16 + r15) * 136) = pack4_fp8(e0, e1, e2, e3);
  }
  barrier_lds();
  // PV phase (fp8): 32-ch slab x 128 keys x both 32-q halves
  const unsigned char* pb = P + pbuf * 8704;
#pragma unroll
  for (int s = 0; s < 8; ++s) {
    long pf0 = (long)*(const u64*)(pb + (size_t)l31 * 136 + s * 16 + lh * 8);
    long pf1 = (long)*(const u64*)(pb + (size_t)(32 + l31) * 136 + s * 16 + lh * 8);
    acc[0] = __builtin_amdgcn_mfma_f32_32x32x16_fp8_fp8((long)vfu[s], pf0, acc[0], 0, 0, 0);
    acc[1] = __builtin_amdgcn_mfma_f32_32x32x16_fp8_fp8((long)vfu[s], pf1, acc[1], 0, 0, 0);
  }
}

__device__ __forceinline__ void attn_loop(
    const unsigned short* __restrict__ Kp, const unsigned char* __restrict__ Vp,
    unsigned char* __restrict__ P, const v8s qf[4], const float m[4], int w, int lane,
    v16f acc[2], float lsum[4]) {
  const unsigned short* Kl = Kp + (size_t)w * 512 + lane * 8;
  const unsigned char* Vl = Vp + (size_t)w * 512 + lane * 8;
  v8s kA, kB;
  u64 vA[8], vB[8];
  kA = *(const v8s*)(Kl);
#pragma unroll
  for (int s = 0; s < 8; ++s) vA[s] = *(const u64*)(Vl + (size_t)s * 4096);
  for (int kt = 0; kt < 32; kt += 2) {
    attn_tile(Kl, Vl, P, qf, m, w, lane, 0, (kt + 1) & 31, kA, vA, kB, vB, acc, lsum);
    attn_tile(Kl, Vl, P, qf, m, w, lane, 1, (kt + 2) & 31, kB, vB, kA, vA, acc, lsum);
  }
}

__global__ __launch_bounds__(512, 2) void fused_attn_kernel(
    const unsigned short* __restrict__ Q1g, const unsigned short* __restrict__ K1g,
    const unsigned char* __restrict__ V1g, const unsigned short* __restrict__ K2g,
    const unsigned char* __restrict__ V2g, const unsigned short* __restrict__ W2g,
    const float* __restrict__ x, const float* __restrict__ q2b,
    const float* __restrict__ g1p, const float* __restrict__ g2p,
    float* __restrict__ outp) {
  __shared__ __align__(16) unsigned char P[2 * 8704];        // 17 KB fp8 P
  __shared__ __align__(16) unsigned short out1T[64 * 264];   // 33.8 KB [q][c] bf16
  __shared__ __align__(16) unsigned short q2s[64 * 32];      // 4 KB [q][o]
  __shared__ float lbuf[8][64];

  const int tid = threadIdx.x;
  const int lane = tid & 63;
  const int w = tid >> 6;
  const int quad = lane >> 4;
  const int r15 = lane & 15;
  const int l31 = lane & 31, lh = lane >> 5;
  const int b = blockIdx.x & 3;
  const int n0 = (blockIdx.x >> 2) * 64;

  const float g1 = g1p[0];
  const float g2 = g2p[0];

  const unsigned short* Qp  = Q1g + (size_t)b * NSEQ * CQKD;
  const unsigned short* K1p = K1g + (size_t)b * (NSEQ / 16) * 512;
  const unsigned short* K2p = K2g + (size_t)b * (NSEQ / 16) * 512;
  const unsigned char* V1p  = V1g + (size_t)b * (NSEQ / 16) * 8 * 512;
  const unsigned char* V2p  = V2g + (size_t)b * (NSEQ / 16) * 8 * 512;

  v8s qf[4];
#pragma unroll
  for (int qt = 0; qt < 4; ++qt)
    qf[qt] = *(const v8s*)(Qp + (n0 + qt * 16 + r15) * CQKD + quad * 8);

  v16f acc[2];
  float lsum[4] = {0.f, 0.f, 0.f, 0.f};
  float m[4];
  acc[0] = (v16f)(0.f); acc[1] = (v16f)(0.f);

  // ---- layer 1 ----
  max_pass(K1p, qf, w, lane, lbuf, m);
  attn_loop(K1p, V1p, P, qf, m, w, lane, acc, lsum);
#pragma unroll
  for (int qt = 0; qt < 4; ++qt) {
    lsum[qt] += __shfl_xor(lsum[qt], 16);
    lsum[qt] += __shfl_xor(lsum[qt], 32);
  }
  __syncthreads();
  if (lane < 16) {
#pragma unroll
    for (int qt = 0; qt < 4; ++qt) lbuf[w][qt * 16 + lane] = lsum[qt];
  }
  __syncthreads();
  float rinv[2];
#pragma unroll
  for (int qh = 0; qh < 2; ++qh) {
    const int q = qh * 32 + l31;
    float d = 0.f;
#pragma unroll
    for (int ww = 0; ww < 8; ++ww) d += lbuf[ww][q];
    rinv[qh] = 1.0f / d;
  }
#pragma unroll
  for (int qh = 0; qh < 2; ++qh) {
    const int q = qh * 32 + l31;
#pragma unroll
    for (int rg = 0; rg < 4; ++rg) {
      const int c = w * 32 + 8 * rg + 4 * lh;
      float o0 = g1 * (acc[qh][rg * 4 + 0] * rinv[qh]) + x[((size_t)b * CDIM + c + 0) * NSEQ + n0 + q];
      float o1 = g1 * (acc[qh][rg * 4 + 1] * rinv[qh]) + x[((size_t)b * CDIM + c + 1) * NSEQ + n0 + q];
      float o2 = g1 * (acc[qh][rg * 4 + 2] * rinv[qh]) + x[((size_t)b * CDIM + c + 2) * NSEQ + n0 + q];
      float o3 = g1 * (acc[qh][rg * 4 + 3] * rinv[qh]) + x[((size_t)b * CDIM + c + 3) * NSEQ + n0 + q];
      uint2 pk;
      pk.x = pack_bf16(o0, o1);
      pk.y = pack_bf16(o2, o3);
      *(uint2*)(out1T + (size_t)q * 264 + c) = pk;
    }
  }
  __syncthreads();

  // ---- q2 projection (waves 0,1): W2 A-frag 32x32x16 bf16, pre-scaled ----
  if (w < 2) {
    const int qh = w;
    v16f qacc = (v16f)(0.f);
#pragma unroll
    for (int s = 0; s < 16; ++s) {
      v8s af = *(const v8s*)(W2g + (size_t)(s * 64 + lane) * 8);
      v8s bf = *(const v8s*)(out1T + (size_t)(qh * 32 + l31) * 264 + s * 16 + lh * 8);
      qacc = __builtin_amdgcn_mfma_f32_32x32x16_bf16(af, bf, qacc, 0, 0, 0);
    }
#pragma unroll
    for (int rg = 0; rg < 4; ++rg) {
      const int o = 8 * rg + 4 * lh;
      uint2 pk;
      pk.x = pack_bf16(qacc[rg * 4 + 0] + q2b[o + 0] * LOG2E, qacc[rg * 4 + 1] + q2b[o + 1] * LOG2E);
      pk.y = pack_bf16(qacc[rg * 4 + 2] + q2b[o + 2] * LOG2E, qacc[rg * 4 + 3] + q2b[o + 3] * LOG2E);
      *(uint2*)(q2s + (size_t)(qh * 32 + l31) * 32 + o) = pk;
    }
  }
  __syncthreads();

  // ---- layer 2 ----
#pragma unroll
  for (int qt = 0; qt < 4; ++qt)
    qf[qt] = *(const v8s*)(q2s + (qt * 16 + r15) * 32 + quad * 8);
  acc[0] = (v16f)(0.f); acc[1] = (v16f)(0.f);
#pragma unroll
  for (int qt = 0; qt < 4; ++qt) lsum[qt] = 0.f;
  max_pass(K2p, qf, w, lane, lbuf, m);
  attn_loop(K2p, V2p, P, qf, m, w, lane, acc, lsum);
#pragma unroll
  for (int qt = 0; qt < 4; ++qt) {
    lsum[qt] += __shfl_xor(lsum[qt], 16);
    lsum[qt] += __shfl_xor(lsum[qt], 32);
  }
  __syncthreads();
  if (lane < 16) {
#pragma unroll
    for (int qt = 0; qt < 4; ++qt) lbuf[w][qt * 16 + lane] = lsum[qt];
  }
  __syncthreads();
#pragma unroll
  for (int qh = 0; qh < 2; ++qh) {
    const int q = qh * 32 + l31;
    float d = 0.f;
#pragma unroll
    for (int ww = 0; ww < 8; ++ww) d += lbuf[ww][q];
    rinv[qh] = 1.0f / d;
  }
#pragma unroll
  for (int qh = 0; qh < 2; ++qh) {
    const int q = qh * 32 + l31;
#pragma unroll
    for (int rg = 0; rg < 4; ++rg) {
      const int c = w * 32 + 8 * rg + 4 * lh;
#pragma unroll
      for (int i = 0; i < 4; ++i) {
        float res = bf2f(out1T[(size_t)q * 264 + c + i]);
        outp[((size_t)b * CDIM + c + i) * NSEQ + n0 + q] =
            g2 * (acc[qh][rg * 4 + i] * rinv[qh]) + res;
      }
    }
  }
}

extern "C" void kernel_launch(void* const* d_in, const int* in_sizes, int n_in,
                              void* d_out, int out_size, void* d_ws, size_t ws_size,
                              hipStream_t stream) {
  const float* x   = (const float*)d_in[0];
  const float* y   = (const float*)d_in[1];
  const float* z   = (const float*)d_in[2];
  const float* q1w = (const float*)d_in[3];
  const float* q1b = (const float*)d_in[4];
  const float* k1w = (const float*)d_in[5];
  const float* k1b = (const float*)d_in[6];
  const float* v1w = (const float*)d_in[7];
  const float* v1b = (const float*)d_in[8];
  const float* g1  = (const float*)d_in[9];
  const float* q2w = (const float*)d_in[10];
  const float* q2b = (const float*)d_in[11];
  const float* k2w = (const float*)d_in[12];
  const float* k2b = (const float*)d_in[13];
  const float* v2w = (const float*)d_in[14];
  const float* v2b = (const float*)d_in[15];
  const float* g2  = (const float*)d_in[16];
  char* ws = (char*)d_ws;
  unsigned short* Wbf = (unsigned short*)(ws);             // 327,680 B
  unsigned short* Q1  = (unsigned short*)(ws + 327680);    // 1 MB
  unsigned short* K1  = (unsigned short*)(ws + 1376256);   // 1 MB
  unsigned short* K2  = (unsigned short*)(ws + 2424832);   // 1 MB
  unsigned char*  V1  = (unsigned char*)(ws + 3473408);    // 4 MB (fp8)
  unsigned char*  V2  = (unsigned char*)(ws + 7667712);    // 4 MB (fp8) -> 11.9 MB total
  float* outp = (float*)d_out;

  convw_kernel<<<dim3(80), 256, 0, stream>>>(q1w, k1w, k2w, q2w, v1w, v2w, Wbf);
  prep_kernel<<<dim3(64, 4, 3), 256, 0, stream>>>(x, y, z, Wbf, q1b, k1b, k2b, v1b,
                                                  v2b, Q1, K1, K2, V1, V2);
  fused_attn_kernel<<<dim3(256), 512, 0, stream>>>(Q1, K1, V1, K2, V2, Wbf + 24576, x,
                                                   q2b, g1, g2, outp);
}